// Round 11
// baseline (653.805 us; speedup 1.0000x reference)
//
#include <hip/hip_runtime.h>

typedef unsigned short u16;
typedef unsigned int   u32;
using short8 = __attribute__((ext_vector_type(8))) short;
using f32x4  = __attribute__((ext_vector_type(4))) float;
using f32x16 = __attribute__((ext_vector_type(16))) float;
using u32x4  = __attribute__((ext_vector_type(4))) unsigned int;

#define S_LEN 4096
#define EMB   768
#define NH    12
#define DH    64

// 0.125 (=1/sqrt(64)) * log2(e): folded into Q so softmax uses exp2 directly
#define QSCALE 0.18033688011112042f

__device__ __forceinline__ u16 f2bf(float f) {
  unsigned int u = __builtin_bit_cast(unsigned int, f);
  u += 0x7fffu + ((u >> 16) & 1u);
  return (u16)(u >> 16);
}

__device__ __forceinline__ u32 cvtpk(float lo, float hi) {
  u32 r;
  asm("v_cvt_pk_bf16_f32 %0, %1, %2" : "=v"(r) : "v"(lo), "v"(hi));
  return r;
}

// Cross-half (lane ^ 32) combines -- PROVEN primitive (R3/R6 passed).
// Raw v_permlane32_swap asm failed both orientations (R4/R5); do not use.
// Struct-copy pipelining (R7) and dual-Q state (R9) spilled to scratch; do not use.
__device__ __forceinline__ float pr_max(float v) {
  return fmaxf(v, __shfl_xor(v, 32));
}
__device__ __forceinline__ float pr_add(float v) {
  return v + __shfl_xor(v, 32);
}

__device__ __forceinline__ float fexp2(float x) {
#if __has_builtin(__builtin_amdgcn_exp2f)
  return __builtin_amdgcn_exp2f(x);
#else
  return exp2f(x);
#endif
}

__device__ __forceinline__ f32x4 mfma16(short8 a, short8 b, f32x4 c) {
  return __builtin_amdgcn_mfma_f32_16x16x32_bf16(a, b, c, 0, 0, 0);
}
__device__ __forceinline__ f32x16 mfma32(short8 a, short8 b, f32x16 c) {
  return __builtin_amdgcn_mfma_f32_32x32x16_bf16(a, b, c, 0, 0, 0);
}

// pack 8 f32 P-values into one PV B-frag (k-slice), R3-proven mapping:
//   lower lane: {own w0, own w1, partner w0, partner w1}
//   upper lane: {partner w2, partner w3, own w2, own w3}
__device__ __forceinline__ short8 pack_frag(u32 w0, u32 w1, u32 w2, u32 w3, bool hi) {
  u32 x0 = (u32)__shfl_xor((int)w0, 32), x1 = (u32)__shfl_xor((int)w1, 32);
  u32 x2 = (u32)__shfl_xor((int)w2, 32), x3 = (u32)__shfl_xor((int)w3, 32);
  u32x4 f = { hi ? x2 : w0, hi ? x3 : w1, hi ? w2 : x0, hi ? w3 : x1 };
  return __builtin_bit_cast(short8, f);
}

// ---------------- conversion / transpose kernels ----------------

__global__ void k_conv_x(const float* __restrict__ x, u16* __restrict__ xb, int n) {
  int i = blockIdx.x * 256 + threadIdx.x;
  if (i < n) xb[i] = f2bf(x[i]);
}

__global__ __launch_bounds__(256) void k_transpose_w(const float* __restrict__ w,
                                                     u16* __restrict__ wt,
                                                     int rows, int cols) {
  __shared__ float tile[32][33];
  int tx = threadIdx.x & 31, ty = threadIdx.x >> 5;
  int kb = blockIdx.x * 32;
  int nb = blockIdx.y * 32;
#pragma unroll
  for (int j = 0; j < 4; j++)
    tile[ty + 8 * j][tx] = w[(size_t)(kb + ty + 8 * j) * cols + nb + tx];
  __syncthreads();
#pragma unroll
  for (int j = 0; j < 4; j++)
    wt[(size_t)(nb + ty + 8 * j) * rows + kb + tx] = f2bf(tile[tx][ty + 8 * j]);
}

// ---------------- QKV GEMM + bias + RoPE epilogue ----------------
__global__ __launch_bounds__(256) void k_qkv(const u16* __restrict__ A,
                                             const u16* __restrict__ Bt,
                                             const float* __restrict__ bias,
                                             u16* __restrict__ Qb,
                                             u16* __restrict__ Kb,
                                             u16* __restrict__ Vt) {
  __shared__ u16 As[128][40];
  __shared__ u16 Bs[128][40];
  int t = threadIdx.x;
  int w = t >> 6, lane = t & 63, g = lane >> 4, c = lane & 15;
  int wr = w >> 1, wc = w & 1;
  int bm = blockIdx.x * 128, bn = blockIdx.y * 128;

  f32x4 acc[4][4];
#pragma unroll
  for (int m = 0; m < 4; m++)
#pragma unroll
    for (int n = 0; n < 4; n++) acc[m][n] = (f32x4){0.f, 0.f, 0.f, 0.f};

  int srow = t >> 1, sseg = (t & 1) * 16;
  for (int bk = 0; bk < EMB; bk += 32) {
    const u16* ga = A  + (size_t)(bm + srow) * EMB + bk + sseg;
    const u16* gb = Bt + (size_t)(bn + srow) * EMB + bk + sseg;
    short8 a0 = *(const short8*)ga, a1 = *(const short8*)(ga + 8);
    short8 b0 = *(const short8*)gb, b1 = *(const short8*)(gb + 8);
    __syncthreads();
    *(short8*)&As[srow][sseg] = a0; *(short8*)&As[srow][sseg + 8] = a1;
    *(short8*)&Bs[srow][sseg] = b0; *(short8*)&Bs[srow][sseg + 8] = b1;
    __syncthreads();
    short8 af[4], bf[4];
#pragma unroll
    for (int m = 0; m < 4; m++) af[m] = *(const short8*)&As[wr * 64 + m * 16 + c][g * 8];
#pragma unroll
    for (int n = 0; n < 4; n++) bf[n] = *(const short8*)&Bs[wc * 64 + n * 16 + c][g * 8];
#pragma unroll
    for (int m = 0; m < 4; m++)
#pragma unroll
      for (int n = 0; n < 4; n++) acc[m][n] = mfma16(af[m], bf[n], acc[m][n]);
  }

  int colbase = bn + wc * 64;
  int sec = colbase / EMB;               // 0=Q 1=K 2=V
  int hh  = (colbase % EMB) / DH;
  float qs = (sec == 0) ? QSCALE : 1.0f;
  float invf[2];
#pragma unroll
  for (int n = 0; n < 2; n++) {
    int d1 = n * 16 + c;
    invf[n] = exp2f(-(float)d1 * (13.287712379549449f / 32.0f));
  }
#pragma unroll
  for (int m = 0; m < 4; m++) {
    int rowb = bm + wr * 64 + m * 16 + 4 * g;
#pragma unroll
    for (int e = 0; e < 4; e++) {
      int srw = rowb + e;
      float v[4];
#pragma unroll
      for (int n = 0; n < 4; n++) v[n] = acc[m][n][e] + bias[colbase + n * 16 + c];
      if (sec == 2) {
#pragma unroll
        for (int n = 0; n < 4; n++)
          Vt[(size_t)(hh * DH + n * 16 + c) * S_LEN + srw] = f2bf(v[n]);
      } else {
        u16* dst = (sec == 0) ? Qb : Kb;
        size_t base = ((size_t)hh * S_LEN + srw) * DH;
#pragma unroll
        for (int n = 0; n < 2; n++) {
          int d1 = n * 16 + c;
          float ang = (float)srw * invf[n];
          float sn, cs;
          sincosf(ang, &sn, &cs);
          float o1 = (v[n] * cs - v[n + 2] * sn) * qs;
          float o2 = (v[n + 2] * cs + v[n] * sn) * qs;
          dst[base + d1]      = f2bf(o1);
          dst[base + d1 + 32] = f2bf(o2);
        }
      }
    }
  }
}

// ---------------- flash attention ----------------
// R6 structure (4-wave KV split per 32-row q-block, LDS-free tiles) +
// balanced XCD-local mapping: XCD x serves 192 consecutive logical slots;
// within-head qb pair-interleave (127,0,126,1,..) makes every XCD's total
// work exactly equal (12384 tile-units) while its KV footprint stays <=2
// heads (2 MB, L2-resident).

template<bool MASKED>
__device__ __forceinline__ void attn_tile(int kv0, int qi, int half,
    const u16* __restrict__ Kh, const u16* __restrict__ Vh,
    short8 qf0, short8 qf1, short8 qf2, short8 qf3,
    f32x16& acc0, f32x16& acc1, float& m, float& l) {
  const u16* kp = Kh + (size_t)(kv0 + qi) * DH + half * 8;
  short8 k0 = *(const short8*)(kp);
  short8 k1 = *(const short8*)(kp + 16);
  short8 k2 = *(const short8*)(kp + 32);
  short8 k3 = *(const short8*)(kp + 48);
  __builtin_amdgcn_s_setprio(1);
  f32x16 sc = {0,0,0,0,0,0,0,0,0,0,0,0,0,0,0,0};
  sc = mfma32(k0, qf0, sc);
  sc = mfma32(k1, qf1, sc);
  sc = mfma32(k2, qf2, sc);
  sc = mfma32(k3, qf3, sc);
  __builtin_amdgcn_s_setprio(0);
  const u16* vp = Vh + (size_t)qi * S_LEN + kv0 + half * 8;
  short8 v00 = *(const short8*)(vp);
  short8 v01 = *(const short8*)(vp + 16);
  short8 v10 = *(const short8*)(vp + (size_t)32 * S_LEN);
  short8 v11 = *(const short8*)(vp + (size_t)32 * S_LEN + 16);
  if (MASKED) {
#pragma unroll
    for (int i = 0; i < 16; i++) {
      int kl = (i & 3) + 8 * (i >> 2) + 4 * half;
      if (kl > qi) sc[i] = -1e30f;
    }
  }
  float t0 = fmaxf(fmaxf(sc[0], sc[1]), fmaxf(sc[2], sc[3]));
  float t1 = fmaxf(fmaxf(sc[4], sc[5]), fmaxf(sc[6], sc[7]));
  float t2 = fmaxf(fmaxf(sc[8], sc[9]), fmaxf(sc[10], sc[11]));
  float t3 = fmaxf(fmaxf(sc[12], sc[13]), fmaxf(sc[14], sc[15]));
  float rmax = pr_max(fmaxf(fmaxf(t0, t1), fmaxf(t2, t3)));
  if (__any(rmax > m + 8.0f)) {
    float mn = fmaxf(m, rmax);
    float f = fexp2(m - mn);
    m = mn; l *= f;
#pragma unroll
    for (int i = 0; i < 16; i++) { acc0[i] *= f; acc1[i] *= f; }
  }
  f32x16 p;
#pragma unroll
  for (int i = 0; i < 16; i++) p[i] = fexp2(sc[i] - m);
  l += ((p[0] + p[1]) + (p[2] + p[3])) + ((p[4] + p[5]) + (p[6] + p[7]))
     + ((p[8] + p[9]) + (p[10] + p[11])) + ((p[12] + p[13]) + (p[14] + p[15]));
  bool hi = (half != 0);
  short8 pa0 = pack_frag(cvtpk(p[0], p[1]),   cvtpk(p[2], p[3]),
                         cvtpk(p[4], p[5]),   cvtpk(p[6], p[7]), hi);
  short8 pa1 = pack_frag(cvtpk(p[8], p[9]),   cvtpk(p[10], p[11]),
                         cvtpk(p[12], p[13]), cvtpk(p[14], p[15]), hi);
  __builtin_amdgcn_s_setprio(1);
  acc0 = mfma32(v00, pa0, acc0);
  acc0 = mfma32(v01, pa1, acc0);
  acc1 = mfma32(v10, pa0, acc1);
  acc1 = mfma32(v11, pa1, acc1);
  __builtin_amdgcn_s_setprio(0);
}

// two unmasked 32-KV tiles per call
__device__ __forceinline__ void attn_tile2(int kv0, int qi, int half,
    const u16* __restrict__ Kh, const u16* __restrict__ Vh,
    short8 qf0, short8 qf1, short8 qf2, short8 qf3,
    f32x16& acc0, f32x16& acc1, float& m, float& l) {
  const u16* kpa = Kh + (size_t)(kv0 + qi) * DH + half * 8;
  const u16* kpb = kpa + (size_t)32 * DH;
  short8 ka0 = *(const short8*)(kpa);
  short8 ka1 = *(const short8*)(kpa + 16);
  short8 ka2 = *(const short8*)(kpa + 32);
  short8 ka3 = *(const short8*)(kpa + 48);
  short8 kb0 = *(const short8*)(kpb);
  short8 kb1 = *(const short8*)(kpb + 16);
  short8 kb2 = *(const short8*)(kpb + 32);
  short8 kb3 = *(const short8*)(kpb + 48);
  __builtin_amdgcn_s_setprio(1);
  f32x16 sa = {0,0,0,0,0,0,0,0,0,0,0,0,0,0,0,0};
  f32x16 sb = {0,0,0,0,0,0,0,0,0,0,0,0,0,0,0,0};
  sa = mfma32(ka0, qf0, sa);
  sb = mfma32(kb0, qf0, sb);
  sa = mfma32(ka1, qf1, sa);
  sb = mfma32(kb1, qf1, sb);
  sa = mfma32(ka2, qf2, sa);
  sb = mfma32(kb2, qf2, sb);
  sa = mfma32(ka3, qf3, sa);
  sb = mfma32(kb3, qf3, sb);
  __builtin_amdgcn_s_setprio(0);
  // issue V loads for both sub-tiles; latency hides under softmax
  const u16* vpa = Vh + (size_t)qi * S_LEN + kv0 + half * 8;
  const u16* vpb = vpa + 32;
  short8 va00 = *(const short8*)(vpa);
  short8 va01 = *(const short8*)(vpa + 16);
  short8 va10 = *(const short8*)(vpa + (size_t)32 * S_LEN);
  short8 va11 = *(const short8*)(vpa + (size_t)32 * S_LEN + 16);
  short8 vb00 = *(const short8*)(vpb);
  short8 vb01 = *(const short8*)(vpb + 16);
  short8 vb10 = *(const short8*)(vpb + (size_t)32 * S_LEN);
  short8 vb11 = *(const short8*)(vpb + (size_t)32 * S_LEN + 16);
  // combined max over both sub-tiles
  float t0 = fmaxf(fmaxf(sa[0], sa[1]), fmaxf(sa[2], sa[3]));
  float t1 = fmaxf(fmaxf(sa[4], sa[5]), fmaxf(sa[6], sa[7]));
  float t2 = fmaxf(fmaxf(sa[8], sa[9]), fmaxf(sa[10], sa[11]));
  float t3 = fmaxf(fmaxf(sa[12], sa[13]), fmaxf(sa[14], sa[15]));
  float u0 = fmaxf(fmaxf(sb[0], sb[1]), fmaxf(sb[2], sb[3]));
  float u1 = fmaxf(fmaxf(sb[4], sb[5]), fmaxf(sb[6], sb[7]));
  float u2 = fmaxf(fmaxf(sb[8], sb[9]), fmaxf(sb[10], sb[11]));
  float u3 = fmaxf(fmaxf(sb[12], sb[13]), fmaxf(sb[14], sb[15]));
  float rmax = pr_max(fmaxf(fmaxf(fmaxf(t0, t1), fmaxf(t2, t3)),
                            fmaxf(fmaxf(u0, u1), fmaxf(u2, u3))));
  if (__any(rmax > m + 8.0f)) {
    float mn = fmaxf(m, rmax);
    float f = fexp2(m - mn);
    m = mn; l *= f;
#pragma unroll
    for (int i = 0; i < 16; i++) { acc0[i] *= f; acc1[i] *= f; }
  }
  f32x16 pa, pb;
#pragma unroll
  for (int i = 0; i < 16; i++) pa[i] = fexp2(sa[i] - m);
#pragma unroll
  for (int i = 0; i < 16; i++) pb[i] = fexp2(sb[i] - m);
  float la = ((pa[0] + pa[1]) + (pa[2] + pa[3])) + ((pa[4] + pa[5]) + (pa[6] + pa[7]))
           + ((pa[8] + pa[9]) + (pa[10] + pa[11])) + ((pa[12] + pa[13]) + (pa[14] + pa[15]));
  float lb = ((pb[0] + pb[1]) + (pb[2] + pb[3])) + ((pb[4] + pb[5]) + (pb[6] + pb[7]))
           + ((pb[8] + pb[9]) + (pb[10] + pb[11])) + ((pb[12] + pb[13]) + (pb[14] + pb[15]));
  l += la + lb;
  bool hi = (half != 0);
  short8 fa0 = pack_frag(cvtpk(pa[0], pa[1]),   cvtpk(pa[2], pa[3]),
                         cvtpk(pa[4], pa[5]),   cvtpk(pa[6], pa[7]), hi);
  short8 fa1 = pack_frag(cvtpk(pa[8], pa[9]),   cvtpk(pa[10], pa[11]),
                         cvtpk(pa[12], pa[13]), cvtpk(pa[14], pa[15]), hi);
  short8 fb0 = pack_frag(cvtpk(pb[0], pb[1]),   cvtpk(pb[2], pb[3]),
                         cvtpk(pb[4], pb[5]),   cvtpk(pb[6], pb[7]), hi);
  short8 fb1 = pack_frag(cvtpk(pb[8], pb[9]),   cvtpk(pb[10], pb[11]),
                         cvtpk(pb[12], pb[13]), cvtpk(pb[14], pb[15]), hi);
  __builtin_amdgcn_s_setprio(1);
  acc0 = mfma32(va00, fa0, acc0);
  acc1 = mfma32(va10, fa0, acc1);
  acc0 = mfma32(va01, fa1, acc0);
  acc1 = mfma32(va11, fa1, acc1);
  acc0 = mfma32(vb00, fb0, acc0);
  acc1 = mfma32(vb10, fb0, acc1);
  acc0 = mfma32(vb01, fb1, acc0);
  acc1 = mfma32(vb11, fb1, acc1);
  __builtin_amdgcn_s_setprio(0);
}

__global__ __launch_bounds__(256, 6) void k_attn(const u16* __restrict__ Q,
                                                 const u16* __restrict__ K,
                                                 const u16* __restrict__ Vt,
                                                 u16* __restrict__ O) {
  __shared__ float Lacc[3][64][33];
  __shared__ float Lml[2][3][32];

  int t = threadIdx.x;
  int w = t >> 6, lane = t & 63;
  int qi = lane & 31, half = lane >> 5;
  // Balanced XCD-local mapping: XCD = b%8 gets logical slots [x*192,(x+1)*192).
  // Within a head, slots pair-interleave qb = (127,0,126,1,...) so any
  // contiguous half-head is exactly half the head's causal work.
  int b = blockIdx.x;
  int logical = (b & 7) * 192 + (b >> 3);
  int h = logical >> 7;
  int slot = logical & 127;
  int qb = (slot & 1) ? (slot >> 1) : (127 - (slot >> 1));

  const u16* Qh = Q  + (size_t)h * S_LEN * DH;
  const u16* Kh = K  + (size_t)h * S_LEN * DH;
  const u16* Vh = Vt + (size_t)h * DH * S_LEN;

  const u16* qp = Qh + (size_t)(qb * 32 + qi) * DH + half * 8;
  short8 qf0 = *(const short8*)(qp);
  short8 qf1 = *(const short8*)(qp + 16);
  short8 qf2 = *(const short8*)(qp + 32);
  short8 qf3 = *(const short8*)(qp + 48);

  f32x16 acc0 = {0,0,0,0,0,0,0,0,0,0,0,0,0,0,0,0};
  f32x16 acc1 = {0,0,0,0,0,0,0,0,0,0,0,0,0,0,0,0};
  float m = -1e30f, l = 0.f;

  int nt = qb + 1;                     // total KV tiles (last one masked)
  int ck = (nt + 3) >> 2;              // tiles per wave
  int start = w * ck;
  int end   = min(start + ck, nt);
  int endu  = min(end, nt - 1);        // unmasked range end
  int tt = start;
#pragma unroll 1
  for (; tt + 1 < endu; tt += 2)
    attn_tile2(tt * 32, qi, half, Kh, Vh, qf0, qf1, qf2, qf3, acc0, acc1, m, l);
  for (; tt < endu; tt++)
    attn_tile<false>(tt * 32, qi, half, Kh, Vh, qf0, qf1, qf2, qf3, acc0, acc1, m, l);
  if (start < nt && end == nt)
    attn_tile<true>((nt - 1) * 32, qi, half, Kh, Vh, qf0, qf1, qf2, qf3, acc0, acc1, m, l);

  // cross-wave merge
  float l2 = pr_add(l);
  if (w > 0) {
#pragma unroll
    for (int i = 0; i < 16; i++) {
      Lacc[w - 1][lane][i]      = acc0[i];
      Lacc[w - 1][lane][16 + i] = acc1[i];
    }
    if (half == 0) { Lml[0][w - 1][qi] = m; Lml[1][w - 1][qi] = l2; }
  }
  __syncthreads();
  if (w == 0) {
    float mw[3], lw[3];
    float M = m;
#pragma unroll
    for (int j = 0; j < 3; j++) { mw[j] = Lml[0][j][qi]; lw[j] = Lml[1][j][qi]; M = fmaxf(M, mw[j]); }
    float f0 = fexp2(m - M);
    float ltot = l2 * f0;
#pragma unroll
    for (int i = 0; i < 16; i++) { acc0[i] *= f0; acc1[i] *= f0; }
#pragma unroll
    for (int j = 0; j < 3; j++) {
      float fj = fexp2(mw[j] - M);
      ltot += lw[j] * fj;
#pragma unroll
      for (int i = 0; i < 16; i++) {
        acc0[i] += fj * Lacc[j][lane][i];
        acc1[i] += fj * Lacc[j][lane][16 + i];
      }
    }
    float rl = 1.0f / ltot;
    u16* orow = O + (size_t)(qb * 32 + qi) * EMB + h * DH;
#pragma unroll
    for (int i = 0; i < 16; i += 2) {
      int dl = (i & 3) + 8 * (i >> 2) + 4 * half;
      u32 wa = cvtpk(acc0[i] * rl, acc0[i + 1] * rl);
      u32 wb = cvtpk(acc1[i] * rl, acc1[i + 1] * rl);
      *(u32*)(orow + dl)      = wa;
      *(u32*)(orow + 32 + dl) = wb;
    }
  }
}

// ---------------- output projection ----------------
__global__ __launch_bounds__(256) void k_out(const u16* __restrict__ A,
                                             const u16* __restrict__ Bt,
                                             const float* __restrict__ bias,
                                             float* __restrict__ out) {
  __shared__ u16 As[128][40];
  __shared__ u16 Bs[128][40];
  int t = threadIdx.x;
  int w = t >> 6, lane = t & 63, g = lane >> 4, c = lane & 15;
  int wr = w >> 1, wc = w & 1;
  int bm = blockIdx.x * 128, bn = blockIdx.y * 128;

  f32x4 acc[4][4];
#pragma unroll
  for (int m = 0; m < 4; m++)
#pragma unroll
    for (int n = 0; n < 4; n++) acc[m][n] = (f32x4){0.f, 0.f, 0.f, 0.f};

  int srow = t >> 1, sseg = (t & 1) * 16;
  for (int bk = 0; bk < EMB; bk += 32) {
    const u16* ga = A  + (size_t)(bm + srow) * EMB + bk + sseg;
    const u16* gb = Bt + (size_t)(bn + srow) * EMB + bk + sseg;
    short8 a0 = *(const short8*)ga, a1 = *(const short8*)(ga + 8);
    short8 b0 = *(const short8*)gb, b1 = *(const short8*)(gb + 8);
    __syncthreads();
    *(short8*)&As[srow][sseg] = a0; *(short8*)&As[srow][sseg + 8] = a1;
    *(short8*)&Bs[srow][sseg] = b0; *(short8*)&Bs[srow][sseg + 8] = b1;
    __syncthreads();
    short8 af[4], bf[4];
#pragma unroll
    for (int m = 0; m < 4; m++) af[m] = *(const short8*)&As[wr * 64 + m * 16 + c][g * 8];
#pragma unroll
    for (int n = 0; n < 4; n++) bf[n] = *(const short8*)&Bs[wc * 64 + n * 16 + c][g * 8];
#pragma unroll
    for (int m = 0; m < 4; m++)
#pragma unroll
      for (int n = 0; n < 4; n++) acc[m][n] = mfma16(af[m], bf[n], acc[m][n]);
  }
  int colbase = bn + wc * 64;
#pragma unroll
  for (int m = 0; m < 4; m++) {
    int rowb = bm + wr * 64 + m * 16 + 4 * g;
#pragma unroll
    for (int e = 0; e < 4; e++) {
      int srw = rowb + e;
#pragma unroll
      for (int n = 0; n < 4; n++) {
        int col = colbase + n * 16 + c;
        out[(size_t)srw * EMB + col] = acc[m][n][e] + bias[col];
      }
    }
  }
}

// ---------------- launcher ----------------

extern "C" void kernel_launch(void* const* d_in, const int* in_sizes, int n_in,
                              void* d_out, int out_size, void* d_ws, size_t ws_size,
                              hipStream_t stream) {
  const float* x    = (const float*)d_in[0];
  const float* Wqkv = (const float*)d_in[2];
  const float* bqkv = (const float*)d_in[3];
  const float* Wout = (const float*)d_in[4];
  const float* bout = (const float*)d_in[5];
  float* out = (float*)d_out;

  char* ws = (char*)d_ws;
  u16* xb     = (u16*)(ws);
  u16* wqkvt  = (u16*)(ws + 6291456);
  u16* woutt  = (u16*)(ws + 9830400);
  u16* Qb     = (u16*)(ws + 11010048);
  u16* Kb     = (u16*)(ws + 17301504);
  u16* Vtb    = (u16*)(ws + 23592960);
  u16* Ob     = (u16*)(ws + 29884416);

  k_conv_x<<<(S_LEN * EMB + 255) / 256, 256, 0, stream>>>(x, xb, S_LEN * EMB);
  k_transpose_w<<<dim3(EMB / 32, 3 * EMB / 32), 256, 0, stream>>>(Wqkv, wqkvt, EMB, 3 * EMB);
  k_transpose_w<<<dim3(EMB / 32, EMB / 32), 256, 0, stream>>>(Wout, woutt, EMB, EMB);

  k_qkv<<<dim3(32, 18), 256, 0, stream>>>(xb, wqkvt, bqkv, Qb, Kb, Vtb);
  k_attn<<<NH * 128, 256, 0, stream>>>(Qb, Kb, Vtb, Ob);
  k_out<<<dim3(32, 6), 256, 0, stream>>>(Ob, woutt, bout, out);
}

// Round 12
// 224.625 us; speedup vs baseline: 2.9107x; 2.9107x over previous
//
#include <hip/hip_runtime.h>

typedef unsigned short u16;
typedef unsigned int   u32;
using short8 = __attribute__((ext_vector_type(8))) short;
using f32x4  = __attribute__((ext_vector_type(4))) float;
using f32x16 = __attribute__((ext_vector_type(16))) float;
using u32x4  = __attribute__((ext_vector_type(4))) unsigned int;

#define S_LEN 4096
#define EMB   768
#define NH    12
#define DH    64

// 0.125 (=1/sqrt(64)) * log2(e): folded into Q so softmax uses exp2 directly
#define QSCALE 0.18033688011112042f

__device__ __forceinline__ u16 f2bf(float f) {
  unsigned int u = __builtin_bit_cast(unsigned int, f);
  u += 0x7fffu + ((u >> 16) & 1u);
  return (u16)(u >> 16);
}

__device__ __forceinline__ u32 cvtpk(float lo, float hi) {
  u32 r;
  asm("v_cvt_pk_bf16_f32 %0, %1, %2" : "=v"(r) : "v"(lo), "v"(hi));
  return r;
}

// Cross-half (lane ^ 32) combines -- PROVEN primitive (R3/R6 passed).
// Raw v_permlane32_swap asm failed both orientations (R4/R5); do not use.
// Struct-copy pipelining (R7) and dual-Q state (R9) spilled; do not use.
// launch_bounds waves/EU >= 4 caused VGPR cap + acc spill (R11); keep (256,3).
__device__ __forceinline__ float pr_max(float v) {
  return fmaxf(v, __shfl_xor(v, 32));
}
__device__ __forceinline__ float pr_add(float v) {
  return v + __shfl_xor(v, 32);
}

__device__ __forceinline__ float fexp2(float x) {
#if __has_builtin(__builtin_amdgcn_exp2f)
  return __builtin_amdgcn_exp2f(x);
#else
  return exp2f(x);
#endif
}

__device__ __forceinline__ f32x4 mfma16(short8 a, short8 b, f32x4 c) {
  return __builtin_amdgcn_mfma_f32_16x16x32_bf16(a, b, c, 0, 0, 0);
}
__device__ __forceinline__ f32x16 mfma32(short8 a, short8 b, f32x16 c) {
  return __builtin_amdgcn_mfma_f32_32x32x16_bf16(a, b, c, 0, 0, 0);
}

// pack 8 f32 P-values into one PV B-frag (k-slice), R3-proven mapping:
//   lower lane: {own w0, own w1, partner w0, partner w1}
//   upper lane: {partner w2, partner w3, own w2, own w3}
__device__ __forceinline__ short8 pack_frag(u32 w0, u32 w1, u32 w2, u32 w3, bool hi) {
  u32 x0 = (u32)__shfl_xor((int)w0, 32), x1 = (u32)__shfl_xor((int)w1, 32);
  u32 x2 = (u32)__shfl_xor((int)w2, 32), x3 = (u32)__shfl_xor((int)w3, 32);
  u32x4 f = { hi ? x2 : w0, hi ? x3 : w1, hi ? w2 : x0, hi ? w3 : x1 };
  return __builtin_bit_cast(short8, f);
}

// ---------------- conversion / transpose kernels ----------------

__global__ void k_conv_x(const float* __restrict__ x, u16* __restrict__ xb, int n) {
  int i = blockIdx.x * 256 + threadIdx.x;
  if (i < n) xb[i] = f2bf(x[i]);
}

__global__ __launch_bounds__(256) void k_transpose_w(const float* __restrict__ w,
                                                     u16* __restrict__ wt,
                                                     int rows, int cols) {
  __shared__ float tile[32][33];
  int tx = threadIdx.x & 31, ty = threadIdx.x >> 5;
  int kb = blockIdx.x * 32;
  int nb = blockIdx.y * 32;
#pragma unroll
  for (int j = 0; j < 4; j++)
    tile[ty + 8 * j][tx] = w[(size_t)(kb + ty + 8 * j) * cols + nb + tx];
  __syncthreads();
#pragma unroll
  for (int j = 0; j < 4; j++)
    wt[(size_t)(nb + ty + 8 * j) * rows + kb + tx] = f2bf(tile[tx][ty + 8 * j]);
}

// ---------------- QKV GEMM + bias + RoPE epilogue ----------------
__global__ __launch_bounds__(256) void k_qkv(const u16* __restrict__ A,
                                             const u16* __restrict__ Bt,
                                             const float* __restrict__ bias,
                                             u16* __restrict__ Qb,
                                             u16* __restrict__ Kb,
                                             u16* __restrict__ Vt) {
  __shared__ u16 As[128][40];
  __shared__ u16 Bs[128][40];
  int t = threadIdx.x;
  int w = t >> 6, lane = t & 63, g = lane >> 4, c = lane & 15;
  int wr = w >> 1, wc = w & 1;
  int bm = blockIdx.x * 128, bn = blockIdx.y * 128;

  f32x4 acc[4][4];
#pragma unroll
  for (int m = 0; m < 4; m++)
#pragma unroll
    for (int n = 0; n < 4; n++) acc[m][n] = (f32x4){0.f, 0.f, 0.f, 0.f};

  int srow = t >> 1, sseg = (t & 1) * 16;
  for (int bk = 0; bk < EMB; bk += 32) {
    const u16* ga = A  + (size_t)(bm + srow) * EMB + bk + sseg;
    const u16* gb = Bt + (size_t)(bn + srow) * EMB + bk + sseg;
    short8 a0 = *(const short8*)ga, a1 = *(const short8*)(ga + 8);
    short8 b0 = *(const short8*)gb, b1 = *(const short8*)(gb + 8);
    __syncthreads();
    *(short8*)&As[srow][sseg] = a0; *(short8*)&As[srow][sseg + 8] = a1;
    *(short8*)&Bs[srow][sseg] = b0; *(short8*)&Bs[srow][sseg + 8] = b1;
    __syncthreads();
    short8 af[4], bf[4];
#pragma unroll
    for (int m = 0; m < 4; m++) af[m] = *(const short8*)&As[wr * 64 + m * 16 + c][g * 8];
#pragma unroll
    for (int n = 0; n < 4; n++) bf[n] = *(const short8*)&Bs[wc * 64 + n * 16 + c][g * 8];
#pragma unroll
    for (int m = 0; m < 4; m++)
#pragma unroll
      for (int n = 0; n < 4; n++) acc[m][n] = mfma16(af[m], bf[n], acc[m][n]);
  }

  int colbase = bn + wc * 64;
  int sec = colbase / EMB;               // 0=Q 1=K 2=V
  int hh  = (colbase % EMB) / DH;
  float qs = (sec == 0) ? QSCALE : 1.0f;
  float invf[2];
#pragma unroll
  for (int n = 0; n < 2; n++) {
    int d1 = n * 16 + c;
    invf[n] = exp2f(-(float)d1 * (13.287712379549449f / 32.0f));
  }
#pragma unroll
  for (int m = 0; m < 4; m++) {
    int rowb = bm + wr * 64 + m * 16 + 4 * g;
#pragma unroll
    for (int e = 0; e < 4; e++) {
      int srw = rowb + e;
      float v[4];
#pragma unroll
      for (int n = 0; n < 4; n++) v[n] = acc[m][n][e] + bias[colbase + n * 16 + c];
      if (sec == 2) {
#pragma unroll
        for (int n = 0; n < 4; n++)
          Vt[(size_t)(hh * DH + n * 16 + c) * S_LEN + srw] = f2bf(v[n]);
      } else {
        u16* dst = (sec == 0) ? Qb : Kb;
        size_t base = ((size_t)hh * S_LEN + srw) * DH;
#pragma unroll
        for (int n = 0; n < 2; n++) {
          int d1 = n * 16 + c;
          float ang = (float)srw * invf[n];
          float sn, cs;
          sincosf(ang, &sn, &cs);
          float o1 = (v[n] * cs - v[n + 2] * sn) * qs;
          float o2 = (v[n + 2] * cs + v[n] * sn) * qs;
          dst[base + d1]      = f2bf(o1);
          dst[base + d1 + 32] = f2bf(o2);
        }
      }
    }
  }
}

// ---------------- flash attention ----------------
// R6 structure (4-wave KV split per 32-row q-block, LDS-free tiles) +
// balanced XCD-local mapping (only change vs R6): XCD x serves logical slots
// [x*192,(x+1)*192); within a head slots pair-interleave qb=(127,0,126,1,..)
// so every XCD gets exactly 12384 tile-units and touches <=2 heads (2 MB KV,
// L2-resident).

template<bool MASKED>
__device__ __forceinline__ void attn_tile(int kv0, int qi, int half,
    const u16* __restrict__ Kh, const u16* __restrict__ Vh,
    short8 qf0, short8 qf1, short8 qf2, short8 qf3,
    f32x16& acc0, f32x16& acc1, float& m, float& l) {
  const u16* kp = Kh + (size_t)(kv0 + qi) * DH + half * 8;
  short8 k0 = *(const short8*)(kp);
  short8 k1 = *(const short8*)(kp + 16);
  short8 k2 = *(const short8*)(kp + 32);
  short8 k3 = *(const short8*)(kp + 48);
  __builtin_amdgcn_s_setprio(1);
  f32x16 sc = {0,0,0,0,0,0,0,0,0,0,0,0,0,0,0,0};
  sc = mfma32(k0, qf0, sc);
  sc = mfma32(k1, qf1, sc);
  sc = mfma32(k2, qf2, sc);
  sc = mfma32(k3, qf3, sc);
  __builtin_amdgcn_s_setprio(0);
  const u16* vp = Vh + (size_t)qi * S_LEN + kv0 + half * 8;
  short8 v00 = *(const short8*)(vp);
  short8 v01 = *(const short8*)(vp + 16);
  short8 v10 = *(const short8*)(vp + (size_t)32 * S_LEN);
  short8 v11 = *(const short8*)(vp + (size_t)32 * S_LEN + 16);
  if (MASKED) {
#pragma unroll
    for (int i = 0; i < 16; i++) {
      int kl = (i & 3) + 8 * (i >> 2) + 4 * half;
      if (kl > qi) sc[i] = -1e30f;
    }
  }
  float t0 = fmaxf(fmaxf(sc[0], sc[1]), fmaxf(sc[2], sc[3]));
  float t1 = fmaxf(fmaxf(sc[4], sc[5]), fmaxf(sc[6], sc[7]));
  float t2 = fmaxf(fmaxf(sc[8], sc[9]), fmaxf(sc[10], sc[11]));
  float t3 = fmaxf(fmaxf(sc[12], sc[13]), fmaxf(sc[14], sc[15]));
  float rmax = pr_max(fmaxf(fmaxf(t0, t1), fmaxf(t2, t3)));
  if (__any(rmax > m + 8.0f)) {
    float mn = fmaxf(m, rmax);
    float f = fexp2(m - mn);
    m = mn; l *= f;
#pragma unroll
    for (int i = 0; i < 16; i++) { acc0[i] *= f; acc1[i] *= f; }
  }
  f32x16 p;
#pragma unroll
  for (int i = 0; i < 16; i++) p[i] = fexp2(sc[i] - m);
  l += ((p[0] + p[1]) + (p[2] + p[3])) + ((p[4] + p[5]) + (p[6] + p[7]))
     + ((p[8] + p[9]) + (p[10] + p[11])) + ((p[12] + p[13]) + (p[14] + p[15]));
  bool hi = (half != 0);
  short8 pa0 = pack_frag(cvtpk(p[0], p[1]),   cvtpk(p[2], p[3]),
                         cvtpk(p[4], p[5]),   cvtpk(p[6], p[7]), hi);
  short8 pa1 = pack_frag(cvtpk(p[8], p[9]),   cvtpk(p[10], p[11]),
                         cvtpk(p[12], p[13]), cvtpk(p[14], p[15]), hi);
  __builtin_amdgcn_s_setprio(1);
  acc0 = mfma32(v00, pa0, acc0);
  acc0 = mfma32(v01, pa1, acc0);
  acc1 = mfma32(v10, pa0, acc1);
  acc1 = mfma32(v11, pa1, acc1);
  __builtin_amdgcn_s_setprio(0);
}

// two unmasked 32-KV tiles per call
__device__ __forceinline__ void attn_tile2(int kv0, int qi, int half,
    const u16* __restrict__ Kh, const u16* __restrict__ Vh,
    short8 qf0, short8 qf1, short8 qf2, short8 qf3,
    f32x16& acc0, f32x16& acc1, float& m, float& l) {
  const u16* kpa = Kh + (size_t)(kv0 + qi) * DH + half * 8;
  const u16* kpb = kpa + (size_t)32 * DH;
  short8 ka0 = *(const short8*)(kpa);
  short8 ka1 = *(const short8*)(kpa + 16);
  short8 ka2 = *(const short8*)(kpa + 32);
  short8 ka3 = *(const short8*)(kpa + 48);
  short8 kb0 = *(const short8*)(kpb);
  short8 kb1 = *(const short8*)(kpb + 16);
  short8 kb2 = *(const short8*)(kpb + 32);
  short8 kb3 = *(const short8*)(kpb + 48);
  __builtin_amdgcn_s_setprio(1);
  f32x16 sa = {0,0,0,0,0,0,0,0,0,0,0,0,0,0,0,0};
  f32x16 sb = {0,0,0,0,0,0,0,0,0,0,0,0,0,0,0,0};
  sa = mfma32(ka0, qf0, sa);
  sb = mfma32(kb0, qf0, sb);
  sa = mfma32(ka1, qf1, sa);
  sb = mfma32(kb1, qf1, sb);
  sa = mfma32(ka2, qf2, sa);
  sb = mfma32(kb2, qf2, sb);
  sa = mfma32(ka3, qf3, sa);
  sb = mfma32(kb3, qf3, sb);
  __builtin_amdgcn_s_setprio(0);
  // issue V loads for both sub-tiles; latency hides under softmax
  const u16* vpa = Vh + (size_t)qi * S_LEN + kv0 + half * 8;
  const u16* vpb = vpa + 32;
  short8 va00 = *(const short8*)(vpa);
  short8 va01 = *(const short8*)(vpa + 16);
  short8 va10 = *(const short8*)(vpa + (size_t)32 * S_LEN);
  short8 va11 = *(const short8*)(vpa + (size_t)32 * S_LEN + 16);
  short8 vb00 = *(const short8*)(vpb);
  short8 vb01 = *(const short8*)(vpb + 16);
  short8 vb10 = *(const short8*)(vpb + (size_t)32 * S_LEN);
  short8 vb11 = *(const short8*)(vpb + (size_t)32 * S_LEN + 16);
  // combined max over both sub-tiles
  float t0 = fmaxf(fmaxf(sa[0], sa[1]), fmaxf(sa[2], sa[3]));
  float t1 = fmaxf(fmaxf(sa[4], sa[5]), fmaxf(sa[6], sa[7]));
  float t2 = fmaxf(fmaxf(sa[8], sa[9]), fmaxf(sa[10], sa[11]));
  float t3 = fmaxf(fmaxf(sa[12], sa[13]), fmaxf(sa[14], sa[15]));
  float u0 = fmaxf(fmaxf(sb[0], sb[1]), fmaxf(sb[2], sb[3]));
  float u1 = fmaxf(fmaxf(sb[4], sb[5]), fmaxf(sb[6], sb[7]));
  float u2 = fmaxf(fmaxf(sb[8], sb[9]), fmaxf(sb[10], sb[11]));
  float u3 = fmaxf(fmaxf(sb[12], sb[13]), fmaxf(sb[14], sb[15]));
  float rmax = pr_max(fmaxf(fmaxf(fmaxf(t0, t1), fmaxf(t2, t3)),
                            fmaxf(fmaxf(u0, u1), fmaxf(u2, u3))));
  if (__any(rmax > m + 8.0f)) {
    float mn = fmaxf(m, rmax);
    float f = fexp2(m - mn);
    m = mn; l *= f;
#pragma unroll
    for (int i = 0; i < 16; i++) { acc0[i] *= f; acc1[i] *= f; }
  }
  f32x16 pa, pb;
#pragma unroll
  for (int i = 0; i < 16; i++) pa[i] = fexp2(sa[i] - m);
#pragma unroll
  for (int i = 0; i < 16; i++) pb[i] = fexp2(sb[i] - m);
  float la = ((pa[0] + pa[1]) + (pa[2] + pa[3])) + ((pa[4] + pa[5]) + (pa[6] + pa[7]))
           + ((pa[8] + pa[9]) + (pa[10] + pa[11])) + ((pa[12] + pa[13]) + (pa[14] + pa[15]));
  float lb = ((pb[0] + pb[1]) + (pb[2] + pb[3])) + ((pb[4] + pb[5]) + (pb[6] + pb[7]))
           + ((pb[8] + pb[9]) + (pb[10] + pb[11])) + ((pb[12] + pb[13]) + (pb[14] + pb[15]));
  l += la + lb;
  bool hi = (half != 0);
  short8 fa0 = pack_frag(cvtpk(pa[0], pa[1]),   cvtpk(pa[2], pa[3]),
                         cvtpk(pa[4], pa[5]),   cvtpk(pa[6], pa[7]), hi);
  short8 fa1 = pack_frag(cvtpk(pa[8], pa[9]),   cvtpk(pa[10], pa[11]),
                         cvtpk(pa[12], pa[13]), cvtpk(pa[14], pa[15]), hi);
  short8 fb0 = pack_frag(cvtpk(pb[0], pb[1]),   cvtpk(pb[2], pb[3]),
                         cvtpk(pb[4], pb[5]),   cvtpk(pb[6], pb[7]), hi);
  short8 fb1 = pack_frag(cvtpk(pb[8], pb[9]),   cvtpk(pb[10], pb[11]),
                         cvtpk(pb[12], pb[13]), cvtpk(pb[14], pb[15]), hi);
  __builtin_amdgcn_s_setprio(1);
  acc0 = mfma32(va00, fa0, acc0);
  acc1 = mfma32(va10, fa0, acc1);
  acc0 = mfma32(va01, fa1, acc0);
  acc1 = mfma32(va11, fa1, acc1);
  acc0 = mfma32(vb00, fb0, acc0);
  acc1 = mfma32(vb10, fb0, acc1);
  acc0 = mfma32(vb01, fb1, acc0);
  acc1 = mfma32(vb11, fb1, acc1);
  __builtin_amdgcn_s_setprio(0);
}

__global__ __launch_bounds__(256, 3) void k_attn(const u16* __restrict__ Q,
                                                 const u16* __restrict__ K,
                                                 const u16* __restrict__ Vt,
                                                 u16* __restrict__ O) {
  __shared__ float Lacc[3][64][33];
  __shared__ float Lml[2][3][32];

  int t = threadIdx.x;
  int w = t >> 6, lane = t & 63;
  int qi = lane & 31, half = lane >> 5;
  // Balanced XCD-local mapping (only change vs R6). XCD = b%8 gets logical
  // slots [x*192,(x+1)*192). Within a head, slots pair-interleave qb so any
  // contiguous span is work-balanced: pairs sum to 129 tile-units.
  int b = blockIdx.x;
  int logical = (b & 7) * 192 + (b >> 3);
  int h = logical >> 7;
  int slot = logical & 127;
  int qb = (slot & 1) ? (slot >> 1) : (127 - (slot >> 1));

  const u16* Qh = Q  + (size_t)h * S_LEN * DH;
  const u16* Kh = K  + (size_t)h * S_LEN * DH;
  const u16* Vh = Vt + (size_t)h * DH * S_LEN;

  const u16* qp = Qh + (size_t)(qb * 32 + qi) * DH + half * 8;
  short8 qf0 = *(const short8*)(qp);
  short8 qf1 = *(const short8*)(qp + 16);
  short8 qf2 = *(const short8*)(qp + 32);
  short8 qf3 = *(const short8*)(qp + 48);

  f32x16 acc0 = {0,0,0,0,0,0,0,0,0,0,0,0,0,0,0,0};
  f32x16 acc1 = {0,0,0,0,0,0,0,0,0,0,0,0,0,0,0,0};
  float m = -1e30f, l = 0.f;

  int nt = qb + 1;                     // total KV tiles (last one masked)
  int ck = (nt + 3) >> 2;              // tiles per wave
  int start = w * ck;
  int end   = min(start + ck, nt);
  int endu  = min(end, nt - 1);        // unmasked range end
  int tt = start;
#pragma unroll 1
  for (; tt + 1 < endu; tt += 2)
    attn_tile2(tt * 32, qi, half, Kh, Vh, qf0, qf1, qf2, qf3, acc0, acc1, m, l);
  for (; tt < endu; tt++)
    attn_tile<false>(tt * 32, qi, half, Kh, Vh, qf0, qf1, qf2, qf3, acc0, acc1, m, l);
  if (start < nt && end == nt)
    attn_tile<true>((nt - 1) * 32, qi, half, Kh, Vh, qf0, qf1, qf2, qf3, acc0, acc1, m, l);

  // cross-wave merge
  float l2 = pr_add(l);
  if (w > 0) {
#pragma unroll
    for (int i = 0; i < 16; i++) {
      Lacc[w - 1][lane][i]      = acc0[i];
      Lacc[w - 1][lane][16 + i] = acc1[i];
    }
    if (half == 0) { Lml[0][w - 1][qi] = m; Lml[1][w - 1][qi] = l2; }
  }
  __syncthreads();
  if (w == 0) {
    float mw[3], lw[3];
    float M = m;
#pragma unroll
    for (int j = 0; j < 3; j++) { mw[j] = Lml[0][j][qi]; lw[j] = Lml[1][j][qi]; M = fmaxf(M, mw[j]); }
    float f0 = fexp2(m - M);
    float ltot = l2 * f0;
#pragma unroll
    for (int i = 0; i < 16; i++) { acc0[i] *= f0; acc1[i] *= f0; }
#pragma unroll
    for (int j = 0; j < 3; j++) {
      float fj = fexp2(mw[j] - M);
      ltot += lw[j] * fj;
#pragma unroll
      for (int i = 0; i < 16; i++) {
        acc0[i] += fj * Lacc[j][lane][i];
        acc1[i] += fj * Lacc[j][lane][16 + i];
      }
    }
    float rl = 1.0f / ltot;
    u16* orow = O + (size_t)(qb * 32 + qi) * EMB + h * DH;
#pragma unroll
    for (int i = 0; i < 16; i += 2) {
      int dl = (i & 3) + 8 * (i >> 2) + 4 * half;
      u32 wa = cvtpk(acc0[i] * rl, acc0[i + 1] * rl);
      u32 wb = cvtpk(acc1[i] * rl, acc1[i + 1] * rl);
      *(u32*)(orow + dl)      = wa;
      *(u32*)(orow + 32 + dl) = wb;
    }
  }
}

// ---------------- output projection ----------------
__global__ __launch_bounds__(256) void k_out(const u16* __restrict__ A,
                                             const u16* __restrict__ Bt,
                                             const float* __restrict__ bias,
                                             float* __restrict__ out) {
  __shared__ u16 As[128][40];
  __shared__ u16 Bs[128][40];
  int t = threadIdx.x;
  int w = t >> 6, lane = t & 63, g = lane >> 4, c = lane & 15;
  int wr = w >> 1, wc = w & 1;
  int bm = blockIdx.x * 128, bn = blockIdx.y * 128;

  f32x4 acc[4][4];
#pragma unroll
  for (int m = 0; m < 4; m++)
#pragma unroll
    for (int n = 0; n < 4; n++) acc[m][n] = (f32x4){0.f, 0.f, 0.f, 0.f};

  int srow = t >> 1, sseg = (t & 1) * 16;
  for (int bk = 0; bk < EMB; bk += 32) {
    const u16* ga = A  + (size_t)(bm + srow) * EMB + bk + sseg;
    const u16* gb = Bt + (size_t)(bn + srow) * EMB + bk + sseg;
    short8 a0 = *(const short8*)ga, a1 = *(const short8*)(ga + 8);
    short8 b0 = *(const short8*)gb, b1 = *(const short8*)(gb + 8);
    __syncthreads();
    *(short8*)&As[srow][sseg] = a0; *(short8*)&As[srow][sseg + 8] = a1;
    *(short8*)&Bs[srow][sseg] = b0; *(short8*)&Bs[srow][sseg + 8] = b1;
    __syncthreads();
    short8 af[4], bf[4];
#pragma unroll
    for (int m = 0; m < 4; m++) af[m] = *(const short8*)&As[wr * 64 + m * 16 + c][g * 8];
#pragma unroll
    for (int n = 0; n < 4; n++) bf[n] = *(const short8*)&Bs[wc * 64 + n * 16 + c][g * 8];
#pragma unroll
    for (int m = 0; m < 4; m++)
#pragma unroll
      for (int n = 0; n < 4; n++) acc[m][n] = mfma16(af[m], bf[n], acc[m][n]);
  }
  int colbase = bn + wc * 64;
#pragma unroll
  for (int m = 0; m < 4; m++) {
    int rowb = bm + wr * 64 + m * 16 + 4 * g;
#pragma unroll
    for (int e = 0; e < 4; e++) {
      int srw = rowb + e;
#pragma unroll
      for (int n = 0; n < 4; n++) {
        int col = colbase + n * 16 + c;
        out[(size_t)srw * EMB + col] = acc[m][n][e] + bias[col];
      }
    }
  }
}

// ---------------- launcher ----------------

extern "C" void kernel_launch(void* const* d_in, const int* in_sizes, int n_in,
                              void* d_out, int out_size, void* d_ws, size_t ws_size,
                              hipStream_t stream) {
  const float* x    = (const float*)d_in[0];
  const float* Wqkv = (const float*)d_in[2];
  const float* bqkv = (const float*)d_in[3];
  const float* Wout = (const float*)d_in[4];
  const float* bout = (const float*)d_in[5];
  float* out = (float*)d_out;

  char* ws = (char*)d_ws;
  u16* xb     = (u16*)(ws);
  u16* wqkvt  = (u16*)(ws + 6291456);
  u16* woutt  = (u16*)(ws + 9830400);
  u16* Qb     = (u16*)(ws + 11010048);
  u16* Kb     = (u16*)(ws + 17301504);
  u16* Vtb    = (u16*)(ws + 23592960);
  u16* Ob     = (u16*)(ws + 29884416);

  k_conv_x<<<(S_LEN * EMB + 255) / 256, 256, 0, stream>>>(x, xb, S_LEN * EMB);
  k_transpose_w<<<dim3(EMB / 32, 3 * EMB / 32), 256, 0, stream>>>(Wqkv, wqkvt, EMB, 3 * EMB);
  k_transpose_w<<<dim3(EMB / 32, EMB / 32), 256, 0, stream>>>(Wout, woutt, EMB, EMB);

  k_qkv<<<dim3(32, 18), 256, 0, stream>>>(xb, wqkvt, bqkv, Qb, Kb, Vtb);
  k_attn<<<NH * 128, 256, 0, stream>>>(Qb, Kb, Vtb, Ob);
  k_out<<<dim3(32, 6), 256, 0, stream>>>(Ob, woutt, bout, out);
}

// Round 13
// 183.362 us; speedup vs baseline: 3.5656x; 1.2250x over previous
//
#include <hip/hip_runtime.h>

typedef unsigned short u16;
typedef unsigned int   u32;
using short8 = __attribute__((ext_vector_type(8))) short;
using f32x4  = __attribute__((ext_vector_type(4))) float;
using f32x16 = __attribute__((ext_vector_type(16))) float;
using u32x4  = __attribute__((ext_vector_type(4))) unsigned int;

#define S_LEN 4096
#define EMB   768
#define NH    12
#define DH    64

// 0.125 (=1/sqrt(64)) * log2(e): folded into Q so softmax uses exp2 directly
#define QSCALE 0.18033688011112042f

__device__ __forceinline__ u16 f2bf(float f) {
  unsigned int u = __builtin_bit_cast(unsigned int, f);
  u += 0x7fffu + ((u >> 16) & 1u);
  return (u16)(u >> 16);
}

__device__ __forceinline__ u32 cvtpk(float lo, float hi) {
  u32 r;
  asm("v_cvt_pk_bf16_f32 %0, %1, %2" : "=v"(r) : "v"(lo), "v"(hi));
  return r;
}

// pack 8 consecutive f32 into 8 bf16 (one short8) via 4 cvt_pk
__device__ __forceinline__ short8 pack8(const float* p) {
  f32x4 x0 = *(const f32x4*)p;
  f32x4 x1 = *(const f32x4*)(p + 4);
  u32x4 r = { cvtpk(x0[0], x0[1]), cvtpk(x0[2], x0[3]),
              cvtpk(x1[0], x1[1]), cvtpk(x1[2], x1[3]) };
  return __builtin_bit_cast(short8, r);
}

// Cross-half (lane ^ 32) combines -- PROVEN primitive (R3/R6 passed).
// Raw v_permlane32_swap asm failed both orientations (R4/R5); do not use.
// Struct-copy pipelining (R7) and dual-Q state (R9) spilled; do not use.
// launch_bounds waves/EU >= 4 caused VGPR cap + acc spill (R11); keep (256,3).
// XCD-local mappings (R8/R12) cut FETCH but regressed time; keep plain map.
__device__ __forceinline__ float pr_max(float v) {
  return fmaxf(v, __shfl_xor(v, 32));
}
__device__ __forceinline__ float pr_add(float v) {
  return v + __shfl_xor(v, 32);
}

__device__ __forceinline__ float fexp2(float x) {
#if __has_builtin(__builtin_amdgcn_exp2f)
  return __builtin_amdgcn_exp2f(x);
#else
  return exp2f(x);
#endif
}

__device__ __forceinline__ f32x4 mfma16(short8 a, short8 b, f32x4 c) {
  return __builtin_amdgcn_mfma_f32_16x16x32_bf16(a, b, c, 0, 0, 0);
}
__device__ __forceinline__ f32x16 mfma32(short8 a, short8 b, f32x16 c) {
  return __builtin_amdgcn_mfma_f32_32x32x16_bf16(a, b, c, 0, 0, 0);
}

// pack 8 f32 P-values into one PV B-frag (k-slice), R3-proven mapping:
//   lower lane: {own w0, own w1, partner w0, partner w1}
//   upper lane: {partner w2, partner w3, own w2, own w3}
__device__ __forceinline__ short8 pack_frag(u32 w0, u32 w1, u32 w2, u32 w3, bool hi) {
  u32 x0 = (u32)__shfl_xor((int)w0, 32), x1 = (u32)__shfl_xor((int)w1, 32);
  u32 x2 = (u32)__shfl_xor((int)w2, 32), x3 = (u32)__shfl_xor((int)w3, 32);
  u32x4 f = { hi ? x2 : w0, hi ? x3 : w1, hi ? w2 : x0, hi ? w3 : x1 };
  return __builtin_bit_cast(short8, f);
}

// ---------------- weight transpose ----------------

__global__ __launch_bounds__(256) void k_transpose_w(const float* __restrict__ w,
                                                     u16* __restrict__ wt,
                                                     int rows, int cols) {
  __shared__ float tile[32][33];
  int tx = threadIdx.x & 31, ty = threadIdx.x >> 5;
  int kb = blockIdx.x * 32;
  int nb = blockIdx.y * 32;
#pragma unroll
  for (int j = 0; j < 4; j++)
    tile[ty + 8 * j][tx] = w[(size_t)(kb + ty + 8 * j) * cols + nb + tx];
  __syncthreads();
#pragma unroll
  for (int j = 0; j < 4; j++)
    wt[(size_t)(nb + ty + 8 * j) * rows + kb + tx] = f2bf(tile[tx][ty + 8 * j]);
}

// ---------------- QKV GEMM (x read as f32, converted in staging) ----------------
__global__ __launch_bounds__(256) void k_qkv(const float* __restrict__ X,
                                             const u16* __restrict__ Bt,
                                             const float* __restrict__ bias,
                                             u16* __restrict__ Qb,
                                             u16* __restrict__ Kb,
                                             u16* __restrict__ Vt) {
  __shared__ u16 As[128][40];
  __shared__ u16 Bs[128][40];
  int t = threadIdx.x;
  int w = t >> 6, lane = t & 63, g = lane >> 4, c = lane & 15;
  int wr = w >> 1, wc = w & 1;
  int bm = blockIdx.x * 128, bn = blockIdx.y * 128;

  f32x4 acc[4][4];
#pragma unroll
  for (int m = 0; m < 4; m++)
#pragma unroll
    for (int n = 0; n < 4; n++) acc[m][n] = (f32x4){0.f, 0.f, 0.f, 0.f};

  int srow = t >> 1, sseg = (t & 1) * 16;
  for (int bk = 0; bk < EMB; bk += 32) {
    const float* gx = X + (size_t)(bm + srow) * EMB + bk + sseg;
    const u16*   gb = Bt + (size_t)(bn + srow) * EMB + bk + sseg;
    short8 a0 = pack8(gx);
    short8 a1 = pack8(gx + 8);
    short8 b0 = *(const short8*)gb, b1 = *(const short8*)(gb + 8);
    __syncthreads();
    *(short8*)&As[srow][sseg] = a0; *(short8*)&As[srow][sseg + 8] = a1;
    *(short8*)&Bs[srow][sseg] = b0; *(short8*)&Bs[srow][sseg + 8] = b1;
    __syncthreads();
    short8 af[4], bf[4];
#pragma unroll
    for (int m = 0; m < 4; m++) af[m] = *(const short8*)&As[wr * 64 + m * 16 + c][g * 8];
#pragma unroll
    for (int n = 0; n < 4; n++) bf[n] = *(const short8*)&Bs[wc * 64 + n * 16 + c][g * 8];
#pragma unroll
    for (int m = 0; m < 4; m++)
#pragma unroll
      for (int n = 0; n < 4; n++) acc[m][n] = mfma16(af[m], bf[n], acc[m][n]);
  }

  int colbase = bn + wc * 64;
  int sec = colbase / EMB;               // 0=Q 1=K 2=V
  int hh  = (colbase % EMB) / DH;
  float qs = (sec == 0) ? QSCALE : 1.0f;
  float invf[2];
#pragma unroll
  for (int n = 0; n < 2; n++) {
    int d1 = n * 16 + c;
    invf[n] = exp2f(-(float)d1 * (13.287712379549449f / 32.0f));
  }
#pragma unroll
  for (int m = 0; m < 4; m++) {
    int rowb = bm + wr * 64 + m * 16 + 4 * g;
#pragma unroll
    for (int e = 0; e < 4; e++) {
      int srw = rowb + e;
      float v[4];
#pragma unroll
      for (int n = 0; n < 4; n++) v[n] = acc[m][n][e] + bias[colbase + n * 16 + c];
      if (sec == 2) {
#pragma unroll
        for (int n = 0; n < 4; n++)
          Vt[(size_t)(hh * DH + n * 16 + c) * S_LEN + srw] = f2bf(v[n]);
      } else {
        u16* dst = (sec == 0) ? Qb : Kb;
        size_t base = ((size_t)hh * S_LEN + srw) * DH;
#pragma unroll
        for (int n = 0; n < 2; n++) {
          int d1 = n * 16 + c;
          float ang = (float)srw * invf[n];
          float sn, cs;
          sincosf(ang, &sn, &cs);
          float o1 = (v[n] * cs - v[n + 2] * sn) * qs;
          float o2 = (v[n + 2] * cs + v[n] * sn) * qs;
          dst[base + d1]      = f2bf(o1);
          dst[base + d1 + 32] = f2bf(o2);
        }
      }
    }
  }
}

// ---------------- flash attention (byte-identical R6 structure) ----------------
// 4-wave KV split per 32-row q-block, LDS-free tiles, plain (h, qb) mapping.

template<bool MASKED>
__device__ __forceinline__ void attn_tile(int kv0, int qi, int half,
    const u16* __restrict__ Kh, const u16* __restrict__ Vh,
    short8 qf0, short8 qf1, short8 qf2, short8 qf3,
    f32x16& acc0, f32x16& acc1, float& m, float& l) {
  const u16* kp = Kh + (size_t)(kv0 + qi) * DH + half * 8;
  short8 k0 = *(const short8*)(kp);
  short8 k1 = *(const short8*)(kp + 16);
  short8 k2 = *(const short8*)(kp + 32);
  short8 k3 = *(const short8*)(kp + 48);
  __builtin_amdgcn_s_setprio(1);
  f32x16 sc = {0,0,0,0,0,0,0,0,0,0,0,0,0,0,0,0};
  sc = mfma32(k0, qf0, sc);
  sc = mfma32(k1, qf1, sc);
  sc = mfma32(k2, qf2, sc);
  sc = mfma32(k3, qf3, sc);
  __builtin_amdgcn_s_setprio(0);
  const u16* vp = Vh + (size_t)qi * S_LEN + kv0 + half * 8;
  short8 v00 = *(const short8*)(vp);
  short8 v01 = *(const short8*)(vp + 16);
  short8 v10 = *(const short8*)(vp + (size_t)32 * S_LEN);
  short8 v11 = *(const short8*)(vp + (size_t)32 * S_LEN + 16);
  if (MASKED) {
#pragma unroll
    for (int i = 0; i < 16; i++) {
      int kl = (i & 3) + 8 * (i >> 2) + 4 * half;
      if (kl > qi) sc[i] = -1e30f;
    }
  }
  float t0 = fmaxf(fmaxf(sc[0], sc[1]), fmaxf(sc[2], sc[3]));
  float t1 = fmaxf(fmaxf(sc[4], sc[5]), fmaxf(sc[6], sc[7]));
  float t2 = fmaxf(fmaxf(sc[8], sc[9]), fmaxf(sc[10], sc[11]));
  float t3 = fmaxf(fmaxf(sc[12], sc[13]), fmaxf(sc[14], sc[15]));
  float rmax = pr_max(fmaxf(fmaxf(t0, t1), fmaxf(t2, t3)));
  if (__any(rmax > m + 8.0f)) {
    float mn = fmaxf(m, rmax);
    float f = fexp2(m - mn);
    m = mn; l *= f;
#pragma unroll
    for (int i = 0; i < 16; i++) { acc0[i] *= f; acc1[i] *= f; }
  }
  f32x16 p;
#pragma unroll
  for (int i = 0; i < 16; i++) p[i] = fexp2(sc[i] - m);
  l += ((p[0] + p[1]) + (p[2] + p[3])) + ((p[4] + p[5]) + (p[6] + p[7]))
     + ((p[8] + p[9]) + (p[10] + p[11])) + ((p[12] + p[13]) + (p[14] + p[15]));
  bool hi = (half != 0);
  short8 pa0 = pack_frag(cvtpk(p[0], p[1]),   cvtpk(p[2], p[3]),
                         cvtpk(p[4], p[5]),   cvtpk(p[6], p[7]), hi);
  short8 pa1 = pack_frag(cvtpk(p[8], p[9]),   cvtpk(p[10], p[11]),
                         cvtpk(p[12], p[13]), cvtpk(p[14], p[15]), hi);
  __builtin_amdgcn_s_setprio(1);
  acc0 = mfma32(v00, pa0, acc0);
  acc0 = mfma32(v01, pa1, acc0);
  acc1 = mfma32(v10, pa0, acc1);
  acc1 = mfma32(v11, pa1, acc1);
  __builtin_amdgcn_s_setprio(0);
}

// two unmasked 32-KV tiles per call
__device__ __forceinline__ void attn_tile2(int kv0, int qi, int half,
    const u16* __restrict__ Kh, const u16* __restrict__ Vh,
    short8 qf0, short8 qf1, short8 qf2, short8 qf3,
    f32x16& acc0, f32x16& acc1, float& m, float& l) {
  const u16* kpa = Kh + (size_t)(kv0 + qi) * DH + half * 8;
  const u16* kpb = kpa + (size_t)32 * DH;
  short8 ka0 = *(const short8*)(kpa);
  short8 ka1 = *(const short8*)(kpa + 16);
  short8 ka2 = *(const short8*)(kpa + 32);
  short8 ka3 = *(const short8*)(kpa + 48);
  short8 kb0 = *(const short8*)(kpb);
  short8 kb1 = *(const short8*)(kpb + 16);
  short8 kb2 = *(const short8*)(kpb + 32);
  short8 kb3 = *(const short8*)(kpb + 48);
  __builtin_amdgcn_s_setprio(1);
  f32x16 sa = {0,0,0,0,0,0,0,0,0,0,0,0,0,0,0,0};
  f32x16 sb = {0,0,0,0,0,0,0,0,0,0,0,0,0,0,0,0};
  sa = mfma32(ka0, qf0, sa);
  sb = mfma32(kb0, qf0, sb);
  sa = mfma32(ka1, qf1, sa);
  sb = mfma32(kb1, qf1, sb);
  sa = mfma32(ka2, qf2, sa);
  sb = mfma32(kb2, qf2, sb);
  sa = mfma32(ka3, qf3, sa);
  sb = mfma32(kb3, qf3, sb);
  __builtin_amdgcn_s_setprio(0);
  const u16* vpa = Vh + (size_t)qi * S_LEN + kv0 + half * 8;
  const u16* vpb = vpa + 32;
  short8 va00 = *(const short8*)(vpa);
  short8 va01 = *(const short8*)(vpa + 16);
  short8 va10 = *(const short8*)(vpa + (size_t)32 * S_LEN);
  short8 va11 = *(const short8*)(vpa + (size_t)32 * S_LEN + 16);
  short8 vb00 = *(const short8*)(vpb);
  short8 vb01 = *(const short8*)(vpb + 16);
  short8 vb10 = *(const short8*)(vpb + (size_t)32 * S_LEN);
  short8 vb11 = *(const short8*)(vpb + (size_t)32 * S_LEN + 16);
  float t0 = fmaxf(fmaxf(sa[0], sa[1]), fmaxf(sa[2], sa[3]));
  float t1 = fmaxf(fmaxf(sa[4], sa[5]), fmaxf(sa[6], sa[7]));
  float t2 = fmaxf(fmaxf(sa[8], sa[9]), fmaxf(sa[10], sa[11]));
  float t3 = fmaxf(fmaxf(sa[12], sa[13]), fmaxf(sa[14], sa[15]));
  float u0 = fmaxf(fmaxf(sb[0], sb[1]), fmaxf(sb[2], sb[3]));
  float u1 = fmaxf(fmaxf(sb[4], sb[5]), fmaxf(sb[6], sb[7]));
  float u2 = fmaxf(fmaxf(sb[8], sb[9]), fmaxf(sb[10], sb[11]));
  float u3 = fmaxf(fmaxf(sb[12], sb[13]), fmaxf(sb[14], sb[15]));
  float rmax = pr_max(fmaxf(fmaxf(fmaxf(t0, t1), fmaxf(t2, t3)),
                            fmaxf(fmaxf(u0, u1), fmaxf(u2, u3))));
  if (__any(rmax > m + 8.0f)) {
    float mn = fmaxf(m, rmax);
    float f = fexp2(m - mn);
    m = mn; l *= f;
#pragma unroll
    for (int i = 0; i < 16; i++) { acc0[i] *= f; acc1[i] *= f; }
  }
  f32x16 pa, pb;
#pragma unroll
  for (int i = 0; i < 16; i++) pa[i] = fexp2(sa[i] - m);
#pragma unroll
  for (int i = 0; i < 16; i++) pb[i] = fexp2(sb[i] - m);
  float la = ((pa[0] + pa[1]) + (pa[2] + pa[3])) + ((pa[4] + pa[5]) + (pa[6] + pa[7]))
           + ((pa[8] + pa[9]) + (pa[10] + pa[11])) + ((pa[12] + pa[13]) + (pa[14] + pa[15]));
  float lb = ((pb[0] + pb[1]) + (pb[2] + pb[3])) + ((pb[4] + pb[5]) + (pb[6] + pb[7]))
           + ((pb[8] + pb[9]) + (pb[10] + pb[11])) + ((pb[12] + pb[13]) + (pb[14] + pb[15]));
  l += la + lb;
  bool hi = (half != 0);
  short8 fa0 = pack_frag(cvtpk(pa[0], pa[1]),   cvtpk(pa[2], pa[3]),
                         cvtpk(pa[4], pa[5]),   cvtpk(pa[6], pa[7]), hi);
  short8 fa1 = pack_frag(cvtpk(pa[8], pa[9]),   cvtpk(pa[10], pa[11]),
                         cvtpk(pa[12], pa[13]), cvtpk(pa[14], pa[15]), hi);
  short8 fb0 = pack_frag(cvtpk(pb[0], pb[1]),   cvtpk(pb[2], pb[3]),
                         cvtpk(pb[4], pb[5]),   cvtpk(pb[6], pb[7]), hi);
  short8 fb1 = pack_frag(cvtpk(pb[8], pb[9]),   cvtpk(pb[10], pb[11]),
                         cvtpk(pb[12], pb[13]), cvtpk(pb[14], pb[15]), hi);
  __builtin_amdgcn_s_setprio(1);
  acc0 = mfma32(va00, fa0, acc0);
  acc1 = mfma32(va10, fa0, acc1);
  acc0 = mfma32(va01, fa1, acc0);
  acc1 = mfma32(va11, fa1, acc1);
  acc0 = mfma32(vb00, fb0, acc0);
  acc1 = mfma32(vb10, fb0, acc1);
  acc0 = mfma32(vb01, fb1, acc0);
  acc1 = mfma32(vb11, fb1, acc1);
  __builtin_amdgcn_s_setprio(0);
}

__global__ __launch_bounds__(256, 3) void k_attn(const u16* __restrict__ Q,
                                                 const u16* __restrict__ K,
                                                 const u16* __restrict__ Vt,
                                                 u16* __restrict__ O) {
  __shared__ float Lacc[3][64][33];
  __shared__ float Lml[2][3][32];

  int t = threadIdx.x;
  int w = t >> 6, lane = t & 63;
  int qi = lane & 31, half = lane >> 5;
  int b = blockIdx.x;
  int h = b % NH;
  int qb = 127 - b / NH;              // longest blocks first

  const u16* Qh = Q  + (size_t)h * S_LEN * DH;
  const u16* Kh = K  + (size_t)h * S_LEN * DH;
  const u16* Vh = Vt + (size_t)h * DH * S_LEN;

  const u16* qp = Qh + (size_t)(qb * 32 + qi) * DH + half * 8;
  short8 qf0 = *(const short8*)(qp);
  short8 qf1 = *(const short8*)(qp + 16);
  short8 qf2 = *(const short8*)(qp + 32);
  short8 qf3 = *(const short8*)(qp + 48);

  f32x16 acc0 = {0,0,0,0,0,0,0,0,0,0,0,0,0,0,0,0};
  f32x16 acc1 = {0,0,0,0,0,0,0,0,0,0,0,0,0,0,0,0};
  float m = -1e30f, l = 0.f;

  int nt = qb + 1;                     // total KV tiles (last one masked)
  int ck = (nt + 3) >> 2;              // tiles per wave
  int start = w * ck;
  int end   = min(start + ck, nt);
  int endu  = min(end, nt - 1);        // unmasked range end
  int tt = start;
#pragma unroll 1
  for (; tt + 1 < endu; tt += 2)
    attn_tile2(tt * 32, qi, half, Kh, Vh, qf0, qf1, qf2, qf3, acc0, acc1, m, l);
  for (; tt < endu; tt++)
    attn_tile<false>(tt * 32, qi, half, Kh, Vh, qf0, qf1, qf2, qf3, acc0, acc1, m, l);
  if (start < nt && end == nt)
    attn_tile<true>((nt - 1) * 32, qi, half, Kh, Vh, qf0, qf1, qf2, qf3, acc0, acc1, m, l);

  // cross-wave merge
  float l2 = pr_add(l);
  if (w > 0) {
#pragma unroll
    for (int i = 0; i < 16; i++) {
      Lacc[w - 1][lane][i]      = acc0[i];
      Lacc[w - 1][lane][16 + i] = acc1[i];
    }
    if (half == 0) { Lml[0][w - 1][qi] = m; Lml[1][w - 1][qi] = l2; }
  }
  __syncthreads();
  if (w == 0) {
    float mw[3], lw[3];
    float M = m;
#pragma unroll
    for (int j = 0; j < 3; j++) { mw[j] = Lml[0][j][qi]; lw[j] = Lml[1][j][qi]; M = fmaxf(M, mw[j]); }
    float f0 = fexp2(m - M);
    float ltot = l2 * f0;
#pragma unroll
    for (int i = 0; i < 16; i++) { acc0[i] *= f0; acc1[i] *= f0; }
#pragma unroll
    for (int j = 0; j < 3; j++) {
      float fj = fexp2(mw[j] - M);
      ltot += lw[j] * fj;
#pragma unroll
      for (int i = 0; i < 16; i++) {
        acc0[i] += fj * Lacc[j][lane][i];
        acc1[i] += fj * Lacc[j][lane][16 + i];
      }
    }
    float rl = 1.0f / ltot;
    u16* orow = O + (size_t)(qb * 32 + qi) * EMB + h * DH;
#pragma unroll
    for (int i = 0; i < 16; i += 2) {
      int dl = (i & 3) + 8 * (i >> 2) + 4 * half;
      u32 wa = cvtpk(acc0[i] * rl, acc0[i + 1] * rl);
      u32 wb = cvtpk(acc1[i] * rl, acc1[i + 1] * rl);
      *(u32*)(orow + dl)      = wa;
      *(u32*)(orow + 32 + dl) = wb;
    }
  }
}

// ---------------- output projection (128x64 tiles, 384 blocks) ----------------
__global__ __launch_bounds__(256) void k_out(const u16* __restrict__ A,
                                             const u16* __restrict__ Bt,
                                             const float* __restrict__ bias,
                                             float* __restrict__ out) {
  __shared__ u16 As[128][40];
  __shared__ u16 Bs[64][40];
  int t = threadIdx.x;
  int w = t >> 6, lane = t & 63, g = lane >> 4, c = lane & 15;
  int bm = blockIdx.x * 128, bn = blockIdx.y * 64;

  f32x4 acc[2][4];
#pragma unroll
  for (int m = 0; m < 2; m++)
#pragma unroll
    for (int n = 0; n < 4; n++) acc[m][n] = (f32x4){0.f, 0.f, 0.f, 0.f};

  int arow = t >> 1, aseg = (t & 1) * 16;   // A: 128 rows x 2 halves
  int brow = t >> 2, bseg = (t & 3) * 8;    // B: 64 rows x 4 chunks
  for (int bk = 0; bk < EMB; bk += 32) {
    const u16* ga = A  + (size_t)(bm + arow) * EMB + bk + aseg;
    const u16* gb = Bt + (size_t)(bn + brow) * EMB + bk + bseg;
    short8 a0 = *(const short8*)ga, a1 = *(const short8*)(ga + 8);
    short8 b0 = *(const short8*)gb;
    __syncthreads();
    *(short8*)&As[arow][aseg] = a0; *(short8*)&As[arow][aseg + 8] = a1;
    *(short8*)&Bs[brow][bseg] = b0;
    __syncthreads();
    short8 af[2], bf[4];
#pragma unroll
    for (int m = 0; m < 2; m++) af[m] = *(const short8*)&As[w * 32 + m * 16 + c][g * 8];
#pragma unroll
    for (int n = 0; n < 4; n++) bf[n] = *(const short8*)&Bs[n * 16 + c][g * 8];
#pragma unroll
    for (int m = 0; m < 2; m++)
#pragma unroll
      for (int n = 0; n < 4; n++) acc[m][n] = mfma16(af[m], bf[n], acc[m][n]);
  }
#pragma unroll
  for (int m = 0; m < 2; m++) {
    int rowb = bm + w * 32 + m * 16 + 4 * g;
#pragma unroll
    for (int e = 0; e < 4; e++) {
      int srw = rowb + e;
#pragma unroll
      for (int n = 0; n < 4; n++) {
        int col = bn + n * 16 + c;
        out[(size_t)srw * EMB + col] = acc[m][n][e] + bias[col];
      }
    }
  }
}

// ---------------- launcher ----------------

extern "C" void kernel_launch(void* const* d_in, const int* in_sizes, int n_in,
                              void* d_out, int out_size, void* d_ws, size_t ws_size,
                              hipStream_t stream) {
  const float* x    = (const float*)d_in[0];
  const float* Wqkv = (const float*)d_in[2];
  const float* bqkv = (const float*)d_in[3];
  const float* Wout = (const float*)d_in[4];
  const float* bout = (const float*)d_in[5];
  float* out = (float*)d_out;

  char* ws = (char*)d_ws;
  u16* wqkvt  = (u16*)(ws + 6291456);
  u16* woutt  = (u16*)(ws + 9830400);
  u16* Qb     = (u16*)(ws + 11010048);
  u16* Kb     = (u16*)(ws + 17301504);
  u16* Vtb    = (u16*)(ws + 23592960);
  u16* Ob     = (u16*)(ws + 29884416);

  k_transpose_w<<<dim3(EMB / 32, 3 * EMB / 32), 256, 0, stream>>>(Wqkv, wqkvt, EMB, 3 * EMB);
  k_transpose_w<<<dim3(EMB / 32, EMB / 32), 256, 0, stream>>>(Wout, woutt, EMB, EMB);

  k_qkv<<<dim3(32, 18), 256, 0, stream>>>(x, wqkvt, bqkv, Qb, Kb, Vtb);
  k_attn<<<NH * 128, 256, 0, stream>>>(Qb, Kb, Vtb, Ob);
  k_out<<<dim3(32, 12), 256, 0, stream>>>(Ob, woutt, bout, out);
}

// Round 14
// 168.253 us; speedup vs baseline: 3.8858x; 1.0898x over previous
//
#include <hip/hip_runtime.h>

typedef unsigned short u16;
typedef unsigned int   u32;
using short8 = __attribute__((ext_vector_type(8))) short;
using f32x4  = __attribute__((ext_vector_type(4))) float;
using f32x16 = __attribute__((ext_vector_type(16))) float;
using u32x4  = __attribute__((ext_vector_type(4))) unsigned int;

#define S_LEN 4096
#define EMB   768
#define NH    12
#define DH    64

// 0.125 (=1/sqrt(64)) * log2(e): folded into Q so softmax uses exp2 directly
#define QSCALE 0.18033688011112042f

__device__ __forceinline__ u16 f2bf(float f) {
  unsigned int u = __builtin_bit_cast(unsigned int, f);
  u += 0x7fffu + ((u >> 16) & 1u);
  return (u16)(u >> 16);
}

__device__ __forceinline__ u32 cvtpk(float lo, float hi) {
  u32 r;
  asm("v_cvt_pk_bf16_f32 %0, %1, %2" : "=v"(r) : "v"(lo), "v"(hi));
  return r;
}

// pack 8 consecutive f32 into 8 bf16 (one short8) via 4 cvt_pk
__device__ __forceinline__ short8 pack8(const float* p) {
  f32x4 x0 = *(const f32x4*)p;
  f32x4 x1 = *(const f32x4*)(p + 4);
  u32x4 r = { cvtpk(x0[0], x0[1]), cvtpk(x0[2], x0[3]),
              cvtpk(x1[0], x1[1]), cvtpk(x1[2], x1[3]) };
  return __builtin_bit_cast(short8, r);
}

// Cross-half (lane ^ 32) combines -- PROVEN primitive (R3/R6 passed).
// Raw v_permlane32_swap asm failed both orientations (R4/R5); do not use.
// Struct-copy pipelining (R7) and dual-Q state (R9) spilled; do not use.
// launch_bounds waves/EU >= 4 caused VGPR cap + acc spill (R11); keep (256,3).
// XCD-local mappings (R8/R12) cut FETCH but regressed time; keep plain map.
// f32-A fusion into k_qkv staging (R13) cost +5us; keep conv separate (prep).
__device__ __forceinline__ float pr_max(float v) {
  return fmaxf(v, __shfl_xor(v, 32));
}
__device__ __forceinline__ float pr_add(float v) {
  return v + __shfl_xor(v, 32);
}

__device__ __forceinline__ float fexp2(float x) {
#if __has_builtin(__builtin_amdgcn_exp2f)
  return __builtin_amdgcn_exp2f(x);
#else
  return exp2f(x);
#endif
}

__device__ __forceinline__ f32x4 mfma16(short8 a, short8 b, f32x4 c) {
  return __builtin_amdgcn_mfma_f32_16x16x32_bf16(a, b, c, 0, 0, 0);
}
__device__ __forceinline__ f32x16 mfma32(short8 a, short8 b, f32x16 c) {
  return __builtin_amdgcn_mfma_f32_32x32x16_bf16(a, b, c, 0, 0, 0);
}

// pack 8 f32 P-values into one PV B-frag (k-slice), R3-proven mapping:
//   lower lane: {own w0, own w1, partner w0, partner w1}
//   upper lane: {partner w2, partner w3, own w2, own w3}
__device__ __forceinline__ short8 pack_frag(u32 w0, u32 w1, u32 w2, u32 w3, bool hi) {
  u32 x0 = (u32)__shfl_xor((int)w0, 32), x1 = (u32)__shfl_xor((int)w1, 32);
  u32 x2 = (u32)__shfl_xor((int)w2, 32), x3 = (u32)__shfl_xor((int)w3, 32);
  u32x4 f = { hi ? x2 : w0, hi ? x3 : w1, hi ? w2 : x0, hi ? w3 : x1 };
  return __builtin_bit_cast(short8, f);
}

// ---------------- fused prep: x->bf16 + both weight transposes ----------------
// blockIdx ranges: [0,1536) conv; [1536,3264) Wqkv transpose; [3264,3840) Wout.

__device__ __forceinline__ void transpose_tile(const float* __restrict__ w,
                                               u16* __restrict__ wt,
                                               int rows, int cols,
                                               int kb, int nb,
                                               float (*tile)[33]) {
  int tx = threadIdx.x & 31, ty = threadIdx.x >> 5;
#pragma unroll
  for (int j = 0; j < 4; j++)
    tile[ty + 8 * j][tx] = w[(size_t)(kb + ty + 8 * j) * cols + nb + tx];
  __syncthreads();
#pragma unroll
  for (int j = 0; j < 4; j++)
    wt[(size_t)(nb + ty + 8 * j) * rows + kb + tx] = f2bf(tile[tx][ty + 8 * j]);
}

__global__ __launch_bounds__(256) void k_prep(const float* __restrict__ x,
                                              u16* __restrict__ xb,
                                              const float* __restrict__ Wqkv,
                                              u16* __restrict__ wqkvt,
                                              const float* __restrict__ Wout,
                                              u16* __restrict__ woutt) {
  __shared__ float tile[32][33];
  int b = blockIdx.x;
  if (b < 1536) {
    int i = (b * 256 + threadIdx.x) * 8;      // 1536*256*8 = 4096*768
    *(short8*)(xb + i) = pack8(x + i);
  } else if (b < 3264) {
    int bb = b - 1536;                         // 24 x 72 tiles
    transpose_tile(Wqkv, wqkvt, EMB, 3 * EMB, (bb % 24) * 32, (bb / 24) * 32, tile);
  } else {
    int bb = b - 3264;                         // 24 x 24 tiles
    transpose_tile(Wout, woutt, EMB, EMB, (bb % 24) * 32, (bb / 24) * 32, tile);
  }
}

// ---------------- QKV GEMM + bias + RoPE epilogue (bf16 A, R6-proven) ----------------
__global__ __launch_bounds__(256) void k_qkv(const u16* __restrict__ A,
                                             const u16* __restrict__ Bt,
                                             const float* __restrict__ bias,
                                             u16* __restrict__ Qb,
                                             u16* __restrict__ Kb,
                                             u16* __restrict__ Vt) {
  __shared__ u16 As[128][40];
  __shared__ u16 Bs[128][40];
  int t = threadIdx.x;
  int w = t >> 6, lane = t & 63, g = lane >> 4, c = lane & 15;
  int wr = w >> 1, wc = w & 1;
  int bm = blockIdx.x * 128, bn = blockIdx.y * 128;

  f32x4 acc[4][4];
#pragma unroll
  for (int m = 0; m < 4; m++)
#pragma unroll
    for (int n = 0; n < 4; n++) acc[m][n] = (f32x4){0.f, 0.f, 0.f, 0.f};

  int srow = t >> 1, sseg = (t & 1) * 16;
  for (int bk = 0; bk < EMB; bk += 32) {
    const u16* ga = A  + (size_t)(bm + srow) * EMB + bk + sseg;
    const u16* gb = Bt + (size_t)(bn + srow) * EMB + bk + sseg;
    short8 a0 = *(const short8*)ga, a1 = *(const short8*)(ga + 8);
    short8 b0 = *(const short8*)gb, b1 = *(const short8*)(gb + 8);
    __syncthreads();
    *(short8*)&As[srow][sseg] = a0; *(short8*)&As[srow][sseg + 8] = a1;
    *(short8*)&Bs[srow][sseg] = b0; *(short8*)&Bs[srow][sseg + 8] = b1;
    __syncthreads();
    short8 af[4], bf[4];
#pragma unroll
    for (int m = 0; m < 4; m++) af[m] = *(const short8*)&As[wr * 64 + m * 16 + c][g * 8];
#pragma unroll
    for (int n = 0; n < 4; n++) bf[n] = *(const short8*)&Bs[wc * 64 + n * 16 + c][g * 8];
#pragma unroll
    for (int m = 0; m < 4; m++)
#pragma unroll
      for (int n = 0; n < 4; n++) acc[m][n] = mfma16(af[m], bf[n], acc[m][n]);
  }

  int colbase = bn + wc * 64;
  int sec = colbase / EMB;               // 0=Q 1=K 2=V
  int hh  = (colbase % EMB) / DH;
  float qs = (sec == 0) ? QSCALE : 1.0f;
  float invf[2];
#pragma unroll
  for (int n = 0; n < 2; n++) {
    int d1 = n * 16 + c;
    invf[n] = exp2f(-(float)d1 * (13.287712379549449f / 32.0f));
  }
#pragma unroll
  for (int m = 0; m < 4; m++) {
    int rowb = bm + wr * 64 + m * 16 + 4 * g;
#pragma unroll
    for (int e = 0; e < 4; e++) {
      int srw = rowb + e;
      float v[4];
#pragma unroll
      for (int n = 0; n < 4; n++) v[n] = acc[m][n][e] + bias[colbase + n * 16 + c];
      if (sec == 2) {
#pragma unroll
        for (int n = 0; n < 4; n++)
          Vt[(size_t)(hh * DH + n * 16 + c) * S_LEN + srw] = f2bf(v[n]);
      } else {
        u16* dst = (sec == 0) ? Qb : Kb;
        size_t base = ((size_t)hh * S_LEN + srw) * DH;
#pragma unroll
        for (int n = 0; n < 2; n++) {
          int d1 = n * 16 + c;
          float ang = (float)srw * invf[n];
          float sn, cs;
          sincosf(ang, &sn, &cs);
          float o1 = (v[n] * cs - v[n + 2] * sn) * qs;
          float o2 = (v[n + 2] * cs + v[n] * sn) * qs;
          dst[base + d1]      = f2bf(o1);
          dst[base + d1 + 32] = f2bf(o2);
        }
      }
    }
  }
}

// ---------------- flash attention (byte-identical R6 structure) ----------------

template<bool MASKED>
__device__ __forceinline__ void attn_tile(int kv0, int qi, int half,
    const u16* __restrict__ Kh, const u16* __restrict__ Vh,
    short8 qf0, short8 qf1, short8 qf2, short8 qf3,
    f32x16& acc0, f32x16& acc1, float& m, float& l) {
  const u16* kp = Kh + (size_t)(kv0 + qi) * DH + half * 8;
  short8 k0 = *(const short8*)(kp);
  short8 k1 = *(const short8*)(kp + 16);
  short8 k2 = *(const short8*)(kp + 32);
  short8 k3 = *(const short8*)(kp + 48);
  __builtin_amdgcn_s_setprio(1);
  f32x16 sc = {0,0,0,0,0,0,0,0,0,0,0,0,0,0,0,0};
  sc = mfma32(k0, qf0, sc);
  sc = mfma32(k1, qf1, sc);
  sc = mfma32(k2, qf2, sc);
  sc = mfma32(k3, qf3, sc);
  __builtin_amdgcn_s_setprio(0);
  const u16* vp = Vh + (size_t)qi * S_LEN + kv0 + half * 8;
  short8 v00 = *(const short8*)(vp);
  short8 v01 = *(const short8*)(vp + 16);
  short8 v10 = *(const short8*)(vp + (size_t)32 * S_LEN);
  short8 v11 = *(const short8*)(vp + (size_t)32 * S_LEN + 16);
  if (MASKED) {
#pragma unroll
    for (int i = 0; i < 16; i++) {
      int kl = (i & 3) + 8 * (i >> 2) + 4 * half;
      if (kl > qi) sc[i] = -1e30f;
    }
  }
  float t0 = fmaxf(fmaxf(sc[0], sc[1]), fmaxf(sc[2], sc[3]));
  float t1 = fmaxf(fmaxf(sc[4], sc[5]), fmaxf(sc[6], sc[7]));
  float t2 = fmaxf(fmaxf(sc[8], sc[9]), fmaxf(sc[10], sc[11]));
  float t3 = fmaxf(fmaxf(sc[12], sc[13]), fmaxf(sc[14], sc[15]));
  float rmax = pr_max(fmaxf(fmaxf(t0, t1), fmaxf(t2, t3)));
  if (__any(rmax > m + 8.0f)) {
    float mn = fmaxf(m, rmax);
    float f = fexp2(m - mn);
    m = mn; l *= f;
#pragma unroll
    for (int i = 0; i < 16; i++) { acc0[i] *= f; acc1[i] *= f; }
  }
  f32x16 p;
#pragma unroll
  for (int i = 0; i < 16; i++) p[i] = fexp2(sc[i] - m);
  l += ((p[0] + p[1]) + (p[2] + p[3])) + ((p[4] + p[5]) + (p[6] + p[7]))
     + ((p[8] + p[9]) + (p[10] + p[11])) + ((p[12] + p[13]) + (p[14] + p[15]));
  bool hi = (half != 0);
  short8 pa0 = pack_frag(cvtpk(p[0], p[1]),   cvtpk(p[2], p[3]),
                         cvtpk(p[4], p[5]),   cvtpk(p[6], p[7]), hi);
  short8 pa1 = pack_frag(cvtpk(p[8], p[9]),   cvtpk(p[10], p[11]),
                         cvtpk(p[12], p[13]), cvtpk(p[14], p[15]), hi);
  __builtin_amdgcn_s_setprio(1);
  acc0 = mfma32(v00, pa0, acc0);
  acc0 = mfma32(v01, pa1, acc0);
  acc1 = mfma32(v10, pa0, acc1);
  acc1 = mfma32(v11, pa1, acc1);
  __builtin_amdgcn_s_setprio(0);
}

// two unmasked 32-KV tiles per call
__device__ __forceinline__ void attn_tile2(int kv0, int qi, int half,
    const u16* __restrict__ Kh, const u16* __restrict__ Vh,
    short8 qf0, short8 qf1, short8 qf2, short8 qf3,
    f32x16& acc0, f32x16& acc1, float& m, float& l) {
  const u16* kpa = Kh + (size_t)(kv0 + qi) * DH + half * 8;
  const u16* kpb = kpa + (size_t)32 * DH;
  short8 ka0 = *(const short8*)(kpa);
  short8 ka1 = *(const short8*)(kpa + 16);
  short8 ka2 = *(const short8*)(kpa + 32);
  short8 ka3 = *(const short8*)(kpa + 48);
  short8 kb0 = *(const short8*)(kpb);
  short8 kb1 = *(const short8*)(kpb + 16);
  short8 kb2 = *(const short8*)(kpb + 32);
  short8 kb3 = *(const short8*)(kpb + 48);
  __builtin_amdgcn_s_setprio(1);
  f32x16 sa = {0,0,0,0,0,0,0,0,0,0,0,0,0,0,0,0};
  f32x16 sb = {0,0,0,0,0,0,0,0,0,0,0,0,0,0,0,0};
  sa = mfma32(ka0, qf0, sa);
  sb = mfma32(kb0, qf0, sb);
  sa = mfma32(ka1, qf1, sa);
  sb = mfma32(kb1, qf1, sb);
  sa = mfma32(ka2, qf2, sa);
  sb = mfma32(kb2, qf2, sb);
  sa = mfma32(ka3, qf3, sa);
  sb = mfma32(kb3, qf3, sb);
  __builtin_amdgcn_s_setprio(0);
  const u16* vpa = Vh + (size_t)qi * S_LEN + kv0 + half * 8;
  const u16* vpb = vpa + 32;
  short8 va00 = *(const short8*)(vpa);
  short8 va01 = *(const short8*)(vpa + 16);
  short8 va10 = *(const short8*)(vpa + (size_t)32 * S_LEN);
  short8 va11 = *(const short8*)(vpa + (size_t)32 * S_LEN + 16);
  short8 vb00 = *(const short8*)(vpb);
  short8 vb01 = *(const short8*)(vpb + 16);
  short8 vb10 = *(const short8*)(vpb + (size_t)32 * S_LEN);
  short8 vb11 = *(const short8*)(vpb + (size_t)32 * S_LEN + 16);
  float t0 = fmaxf(fmaxf(sa[0], sa[1]), fmaxf(sa[2], sa[3]));
  float t1 = fmaxf(fmaxf(sa[4], sa[5]), fmaxf(sa[6], sa[7]));
  float t2 = fmaxf(fmaxf(sa[8], sa[9]), fmaxf(sa[10], sa[11]));
  float t3 = fmaxf(fmaxf(sa[12], sa[13]), fmaxf(sa[14], sa[15]));
  float u0 = fmaxf(fmaxf(sb[0], sb[1]), fmaxf(sb[2], sb[3]));
  float u1 = fmaxf(fmaxf(sb[4], sb[5]), fmaxf(sb[6], sb[7]));
  float u2 = fmaxf(fmaxf(sb[8], sb[9]), fmaxf(sb[10], sb[11]));
  float u3 = fmaxf(fmaxf(sb[12], sb[13]), fmaxf(sb[14], sb[15]));
  float rmax = pr_max(fmaxf(fmaxf(fmaxf(t0, t1), fmaxf(t2, t3)),
                            fmaxf(fmaxf(u0, u1), fmaxf(u2, u3))));
  if (__any(rmax > m + 8.0f)) {
    float mn = fmaxf(m, rmax);
    float f = fexp2(m - mn);
    m = mn; l *= f;
#pragma unroll
    for (int i = 0; i < 16; i++) { acc0[i] *= f; acc1[i] *= f; }
  }
  f32x16 pa, pb;
#pragma unroll
  for (int i = 0; i < 16; i++) pa[i] = fexp2(sa[i] - m);
#pragma unroll
  for (int i = 0; i < 16; i++) pb[i] = fexp2(sb[i] - m);
  float la = ((pa[0] + pa[1]) + (pa[2] + pa[3])) + ((pa[4] + pa[5]) + (pa[6] + pa[7]))
           + ((pa[8] + pa[9]) + (pa[10] + pa[11])) + ((pa[12] + pa[13]) + (pa[14] + pa[15]));
  float lb = ((pb[0] + pb[1]) + (pb[2] + pb[3])) + ((pb[4] + pb[5]) + (pb[6] + pb[7]))
           + ((pb[8] + pb[9]) + (pb[10] + pb[11])) + ((pb[12] + pb[13]) + (pb[14] + pb[15]));
  l += la + lb;
  bool hi = (half != 0);
  short8 fa0 = pack_frag(cvtpk(pa[0], pa[1]),   cvtpk(pa[2], pa[3]),
                         cvtpk(pa[4], pa[5]),   cvtpk(pa[6], pa[7]), hi);
  short8 fa1 = pack_frag(cvtpk(pa[8], pa[9]),   cvtpk(pa[10], pa[11]),
                         cvtpk(pa[12], pa[13]), cvtpk(pa[14], pa[15]), hi);
  short8 fb0 = pack_frag(cvtpk(pb[0], pb[1]),   cvtpk(pb[2], pb[3]),
                         cvtpk(pb[4], pb[5]),   cvtpk(pb[6], pb[7]), hi);
  short8 fb1 = pack_frag(cvtpk(pb[8], pb[9]),   cvtpk(pb[10], pb[11]),
                         cvtpk(pb[12], pb[13]), cvtpk(pb[14], pb[15]), hi);
  __builtin_amdgcn_s_setprio(1);
  acc0 = mfma32(va00, fa0, acc0);
  acc1 = mfma32(va10, fa0, acc1);
  acc0 = mfma32(va01, fa1, acc0);
  acc1 = mfma32(va11, fa1, acc1);
  acc0 = mfma32(vb00, fb0, acc0);
  acc1 = mfma32(vb10, fb0, acc1);
  acc0 = mfma32(vb01, fb1, acc0);
  acc1 = mfma32(vb11, fb1, acc1);
  __builtin_amdgcn_s_setprio(0);
}

__global__ __launch_bounds__(256, 3) void k_attn(const u16* __restrict__ Q,
                                                 const u16* __restrict__ K,
                                                 const u16* __restrict__ Vt,
                                                 u16* __restrict__ O) {
  __shared__ float Lacc[3][64][33];
  __shared__ float Lml[2][3][32];

  int t = threadIdx.x;
  int w = t >> 6, lane = t & 63;
  int qi = lane & 31, half = lane >> 5;
  int b = blockIdx.x;
  int h = b % NH;
  int qb = 127 - b / NH;              // longest blocks first

  const u16* Qh = Q  + (size_t)h * S_LEN * DH;
  const u16* Kh = K  + (size_t)h * S_LEN * DH;
  const u16* Vh = Vt + (size_t)h * DH * S_LEN;

  const u16* qp = Qh + (size_t)(qb * 32 + qi) * DH + half * 8;
  short8 qf0 = *(const short8*)(qp);
  short8 qf1 = *(const short8*)(qp + 16);
  short8 qf2 = *(const short8*)(qp + 32);
  short8 qf3 = *(const short8*)(qp + 48);

  f32x16 acc0 = {0,0,0,0,0,0,0,0,0,0,0,0,0,0,0,0};
  f32x16 acc1 = {0,0,0,0,0,0,0,0,0,0,0,0,0,0,0,0};
  float m = -1e30f, l = 0.f;

  int nt = qb + 1;                     // total KV tiles (last one masked)
  int ck = (nt + 3) >> 2;              // tiles per wave
  int start = w * ck;
  int end   = min(start + ck, nt);
  int endu  = min(end, nt - 1);        // unmasked range end
  int tt = start;
#pragma unroll 1
  for (; tt + 1 < endu; tt += 2)
    attn_tile2(tt * 32, qi, half, Kh, Vh, qf0, qf1, qf2, qf3, acc0, acc1, m, l);
  for (; tt < endu; tt++)
    attn_tile<false>(tt * 32, qi, half, Kh, Vh, qf0, qf1, qf2, qf3, acc0, acc1, m, l);
  if (start < nt && end == nt)
    attn_tile<true>((nt - 1) * 32, qi, half, Kh, Vh, qf0, qf1, qf2, qf3, acc0, acc1, m, l);

  // cross-wave merge
  float l2 = pr_add(l);
  if (w > 0) {
#pragma unroll
    for (int i = 0; i < 16; i++) {
      Lacc[w - 1][lane][i]      = acc0[i];
      Lacc[w - 1][lane][16 + i] = acc1[i];
    }
    if (half == 0) { Lml[0][w - 1][qi] = m; Lml[1][w - 1][qi] = l2; }
  }
  __syncthreads();
  if (w == 0) {
    float mw[3], lw[3];
    float M = m;
#pragma unroll
    for (int j = 0; j < 3; j++) { mw[j] = Lml[0][j][qi]; lw[j] = Lml[1][j][qi]; M = fmaxf(M, mw[j]); }
    float f0 = fexp2(m - M);
    float ltot = l2 * f0;
#pragma unroll
    for (int i = 0; i < 16; i++) { acc0[i] *= f0; acc1[i] *= f0; }
#pragma unroll
    for (int j = 0; j < 3; j++) {
      float fj = fexp2(mw[j] - M);
      ltot += lw[j] * fj;
#pragma unroll
      for (int i = 0; i < 16; i++) {
        acc0[i] += fj * Lacc[j][lane][i];
        acc1[i] += fj * Lacc[j][lane][16 + i];
      }
    }
    float rl = 1.0f / ltot;
    u16* orow = O + (size_t)(qb * 32 + qi) * EMB + h * DH;
#pragma unroll
    for (int i = 0; i < 16; i += 2) {
      int dl = (i & 3) + 8 * (i >> 2) + 4 * half;
      u32 wa = cvtpk(acc0[i] * rl, acc0[i + 1] * rl);
      u32 wb = cvtpk(acc1[i] * rl, acc1[i + 1] * rl);
      *(u32*)(orow + dl)      = wa;
      *(u32*)(orow + 32 + dl) = wb;
    }
  }
}

// ---------------- output projection (128x64 tiles, 384 blocks) ----------------
__global__ __launch_bounds__(256) void k_out(const u16* __restrict__ A,
                                             const u16* __restrict__ Bt,
                                             const float* __restrict__ bias,
                                             float* __restrict__ out) {
  __shared__ u16 As[128][40];
  __shared__ u16 Bs[64][40];
  int t = threadIdx.x;
  int w = t >> 6, lane = t & 63, g = lane >> 4, c = lane & 15;
  int bm = blockIdx.x * 128, bn = blockIdx.y * 64;

  f32x4 acc[2][4];
#pragma unroll
  for (int m = 0; m < 2; m++)
#pragma unroll
    for (int n = 0; n < 4; n++) acc[m][n] = (f32x4){0.f, 0.f, 0.f, 0.f};

  int arow = t >> 1, aseg = (t & 1) * 16;   // A: 128 rows x 2 halves
  int brow = t >> 2, bseg = (t & 3) * 8;    // B: 64 rows x 4 chunks
  for (int bk = 0; bk < EMB; bk += 32) {
    const u16* ga = A  + (size_t)(bm + arow) * EMB + bk + aseg;
    const u16* gb = Bt + (size_t)(bn + brow) * EMB + bk + bseg;
    short8 a0 = *(const short8*)ga, a1 = *(const short8*)(ga + 8);
    short8 b0 = *(const short8*)gb;
    __syncthreads();
    *(short8*)&As[arow][aseg] = a0; *(short8*)&As[arow][aseg + 8] = a1;
    *(short8*)&Bs[brow][bseg] = b0;
    __syncthreads();
    short8 af[2], bf[4];
#pragma unroll
    for (int m = 0; m < 2; m++) af[m] = *(const short8*)&As[w * 32 + m * 16 + c][g * 8];
#pragma unroll
    for (int n = 0; n < 4; n++) bf[n] = *(const short8*)&Bs[n * 16 + c][g * 8];
#pragma unroll
    for (int m = 0; m < 2; m++)
#pragma unroll
      for (int n = 0; n < 4; n++) acc[m][n] = mfma16(af[m], bf[n], acc[m][n]);
  }
#pragma unroll
  for (int m = 0; m < 2; m++) {
    int rowb = bm + w * 32 + m * 16 + 4 * g;
#pragma unroll
    for (int e = 0; e < 4; e++) {
      int srw = rowb + e;
#pragma unroll
      for (int n = 0; n < 4; n++) {
        int col = bn + n * 16 + c;
        out[(size_t)srw * EMB + col] = acc[m][n][e] + bias[col];
      }
    }
  }
}

// ---------------- launcher ----------------

extern "C" void kernel_launch(void* const* d_in, const int* in_sizes, int n_in,
                              void* d_out, int out_size, void* d_ws, size_t ws_size,
                              hipStream_t stream) {
  const float* x    = (const float*)d_in[0];
  const float* Wqkv = (const float*)d_in[2];
  const float* bqkv = (const float*)d_in[3];
  const float* Wout = (const float*)d_in[4];
  const float* bout = (const float*)d_in[5];
  float* out = (float*)d_out;

  char* ws = (char*)d_ws;
  u16* xb     = (u16*)(ws);
  u16* wqkvt  = (u16*)(ws + 6291456);
  u16* woutt  = (u16*)(ws + 9830400);
  u16* Qb     = (u16*)(ws + 11010048);
  u16* Kb     = (u16*)(ws + 17301504);
  u16* Vtb    = (u16*)(ws + 23592960);
  u16* Ob     = (u16*)(ws + 29884416);

  k_prep<<<3840, 256, 0, stream>>>(x, xb, Wqkv, wqkvt, Wout, woutt);
  k_qkv<<<dim3(32, 18), 256, 0, stream>>>(xb, wqkvt, bqkv, Qb, Kb, Vtb);
  k_attn<<<NH * 128, 256, 0, stream>>>(Qb, Kb, Vtb, Ob);
  k_out<<<dim3(32, 12), 256, 0, stream>>>(Ob, woutt, bout, out);
}

// Round 15
// 152.487 us; speedup vs baseline: 4.2876x; 1.1034x over previous
//
#include <hip/hip_runtime.h>

typedef unsigned short u16;
typedef unsigned int   u32;
using short8 = __attribute__((ext_vector_type(8))) short;
using f32x4  = __attribute__((ext_vector_type(4))) float;
using f32x16 = __attribute__((ext_vector_type(16))) float;
using u32x4  = __attribute__((ext_vector_type(4))) unsigned int;

#define S_LEN 4096
#define EMB   768
#define NH    12
#define DH    64

// 0.125 (=1/sqrt(64)) * log2(e): folded into Q so softmax uses exp2 directly
#define QSCALE 0.18033688011112042f

__device__ __forceinline__ u16 f2bf(float f) {
  unsigned int u = __builtin_bit_cast(unsigned int, f);
  u += 0x7fffu + ((u >> 16) & 1u);
  return (u16)(u >> 16);
}

__device__ __forceinline__ u32 cvtpk(float lo, float hi) {
  u32 r;
  asm("v_cvt_pk_bf16_f32 %0, %1, %2" : "=v"(r) : "v"(lo), "v"(hi));
  return r;
}

// pack 8 consecutive f32 into 8 bf16 (one short8) via 4 cvt_pk
__device__ __forceinline__ short8 pack8(const float* p) {
  f32x4 x0 = *(const f32x4*)p;
  f32x4 x1 = *(const f32x4*)(p + 4);
  u32x4 r = { cvtpk(x0[0], x0[1]), cvtpk(x0[2], x0[3]),
              cvtpk(x1[0], x1[1]), cvtpk(x1[2], x1[3]) };
  return __builtin_bit_cast(short8, r);
}

// async global->LDS, 16B per lane; LDS dest must be base + lane*16 (linear).
__device__ __forceinline__ void gld16(const void* g, void* l) {
  __builtin_amdgcn_global_load_lds(
      (const __attribute__((address_space(1))) void*)g,
      (__attribute__((address_space(3))) void*)l, 16, 0, 0);
}

// Cross-half (lane ^ 32) combines -- PROVEN primitive (R3/R6 passed).
// Raw v_permlane32_swap asm failed both orientations (R4/R5); do not use.
// Struct-copy pipelining (R7) and dual-Q state (R9) spilled; do not use.
// launch_bounds waves/EU >= 4 caused VGPR cap + acc spill (R11); keep (256,3).
// XCD-local mappings (R8/R12) cut FETCH but regressed time; keep plain map.
// f32-A fusion into k_qkv staging (R13) cost +5us; keep conv in prep kernel.
__device__ __forceinline__ float pr_max(float v) {
  return fmaxf(v, __shfl_xor(v, 32));
}
__device__ __forceinline__ float pr_add(float v) {
  return v + __shfl_xor(v, 32);
}

__device__ __forceinline__ float fexp2(float x) {
#if __has_builtin(__builtin_amdgcn_exp2f)
  return __builtin_amdgcn_exp2f(x);
#else
  return exp2f(x);
#endif
}

__device__ __forceinline__ f32x4 mfma16(short8 a, short8 b, f32x4 c) {
  return __builtin_amdgcn_mfma_f32_16x16x32_bf16(a, b, c, 0, 0, 0);
}
__device__ __forceinline__ f32x16 mfma32(short8 a, short8 b, f32x16 c) {
  return __builtin_amdgcn_mfma_f32_32x32x16_bf16(a, b, c, 0, 0, 0);
}

// pack 8 f32 P-values into one PV B-frag (k-slice), R3-proven mapping:
//   lower lane: {own w0, own w1, partner w0, partner w1}
//   upper lane: {partner w2, partner w3, own w2, own w3}
__device__ __forceinline__ short8 pack_frag(u32 w0, u32 w1, u32 w2, u32 w3, bool hi) {
  u32 x0 = (u32)__shfl_xor((int)w0, 32), x1 = (u32)__shfl_xor((int)w1, 32);
  u32 x2 = (u32)__shfl_xor((int)w2, 32), x3 = (u32)__shfl_xor((int)w3, 32);
  u32x4 f = { hi ? x2 : w0, hi ? x3 : w1, hi ? w2 : x0, hi ? w3 : x1 };
  return __builtin_bit_cast(short8, f);
}

// ---------------- fused prep: x->bf16 + both weight transposes ----------------
// blockIdx ranges: [0,1536) conv; [1536,3264) Wqkv transpose; [3264,3840) Wout.

__device__ __forceinline__ void transpose_tile(const float* __restrict__ w,
                                               u16* __restrict__ wt,
                                               int rows, int cols,
                                               int kb, int nb,
                                               float (*tile)[33]) {
  int tx = threadIdx.x & 31, ty = threadIdx.x >> 5;
#pragma unroll
  for (int j = 0; j < 4; j++)
    tile[ty + 8 * j][tx] = w[(size_t)(kb + ty + 8 * j) * cols + nb + tx];
  __syncthreads();
#pragma unroll
  for (int j = 0; j < 4; j++)
    wt[(size_t)(nb + ty + 8 * j) * rows + kb + tx] = f2bf(tile[tx][ty + 8 * j]);
}

__global__ __launch_bounds__(256) void k_prep(const float* __restrict__ x,
                                              u16* __restrict__ xb,
                                              const float* __restrict__ Wqkv,
                                              u16* __restrict__ wqkvt,
                                              const float* __restrict__ Wout,
                                              u16* __restrict__ woutt) {
  __shared__ float tile[32][33];
  int b = blockIdx.x;
  if (b < 1536) {
    int i = (b * 256 + threadIdx.x) * 8;      // 1536*256*8 = 4096*768
    *(short8*)(xb + i) = pack8(x + i);
  } else if (b < 3264) {
    int bb = b - 1536;                         // 24 x 72 tiles
    transpose_tile(Wqkv, wqkvt, EMB, 3 * EMB, (bb % 24) * 32, (bb / 24) * 32, tile);
  } else {
    int bb = b - 3264;                         // 24 x 24 tiles
    transpose_tile(Wout, woutt, EMB, EMB, (bb % 24) * 32, (bb / 24) * 32, tile);
  }
}

// ---------------- QKV GEMM + bias + RoPE epilogue ----------------
// global_load_lds staging (m97 pattern): linear LDS [128][32], thread t's
// dest = base + t*16B, per-lane global src; 2 barriers per K-step.
__global__ __launch_bounds__(256) void k_qkv(const u16* __restrict__ A,
                                             const u16* __restrict__ Bt,
                                             const float* __restrict__ bias,
                                             u16* __restrict__ Qb,
                                             u16* __restrict__ Kb,
                                             u16* __restrict__ Vt) {
  __shared__ u16 AsL[128 * 32];
  __shared__ u16 BsL[128 * 32];
  int t = threadIdx.x;
  int w = t >> 6, lane = t & 63, g = lane >> 4, c = lane & 15;
  int wr = w >> 1, wc = w & 1;
  int bm = blockIdx.x * 128, bn = blockIdx.y * 128;

  f32x4 acc[4][4];
#pragma unroll
  for (int m = 0; m < 4; m++)
#pragma unroll
    for (int n = 0; n < 4; n++) acc[m][n] = (f32x4){0.f, 0.f, 0.f, 0.f};

  // staging map: element e = i*256+t (16B each); row = e>>2, colchunk = e&3
  int r0 = t >> 2, cc0 = (t & 3) * 8;          // i=0
  int r1 = (256 + t) >> 2;                     // i=1 (cc same as cc0)
  const u16* ga0 = A  + (size_t)(bm + r0) * EMB + cc0;
  const u16* ga1 = A  + (size_t)(bm + r1) * EMB + cc0;
  const u16* gb0 = Bt + (size_t)(bn + r0) * EMB + cc0;
  const u16* gb1 = Bt + (size_t)(bn + r1) * EMB + cc0;

  for (int bk = 0; bk < EMB; bk += 32) {
    __syncthreads();                           // previous tile fully consumed
    gld16(ga0 + bk, &AsL[(size_t)t * 8]);
    gld16(ga1 + bk, &AsL[(size_t)(256 + t) * 8]);
    gld16(gb0 + bk, &BsL[(size_t)t * 8]);
    gld16(gb1 + bk, &BsL[(size_t)(256 + t) * 8]);
    __syncthreads();                           // drains vmcnt(0): data visible
    short8 af[4], bf[4];
#pragma unroll
    for (int m = 0; m < 4; m++) af[m] = *(const short8*)&AsL[(wr * 64 + m * 16 + c) * 32 + g * 8];
#pragma unroll
    for (int n = 0; n < 4; n++) bf[n] = *(const short8*)&BsL[(wc * 64 + n * 16 + c) * 32 + g * 8];
#pragma unroll
    for (int m = 0; m < 4; m++)
#pragma unroll
      for (int n = 0; n < 4; n++) acc[m][n] = mfma16(af[m], bf[n], acc[m][n]);
  }

  int colbase = bn + wc * 64;
  int sec = colbase / EMB;               // 0=Q 1=K 2=V
  int hh  = (colbase % EMB) / DH;
  float qs = (sec == 0) ? QSCALE : 1.0f;
  float invf[2];
#pragma unroll
  for (int n = 0; n < 2; n++) {
    int d1 = n * 16 + c;
    invf[n] = exp2f(-(float)d1 * (13.287712379549449f / 32.0f));
  }
#pragma unroll
  for (int m = 0; m < 4; m++) {
    int rowb = bm + wr * 64 + m * 16 + 4 * g;
#pragma unroll
    for (int e = 0; e < 4; e++) {
      int srw = rowb + e;
      float v[4];
#pragma unroll
      for (int n = 0; n < 4; n++) v[n] = acc[m][n][e] + bias[colbase + n * 16 + c];
      if (sec == 2) {
#pragma unroll
        for (int n = 0; n < 4; n++)
          Vt[(size_t)(hh * DH + n * 16 + c) * S_LEN + srw] = f2bf(v[n]);
      } else {
        u16* dst = (sec == 0) ? Qb : Kb;
        size_t base = ((size_t)hh * S_LEN + srw) * DH;
#pragma unroll
        for (int n = 0; n < 2; n++) {
          int d1 = n * 16 + c;
          float ang = (float)srw * invf[n];
          float sn, cs;
          sincosf(ang, &sn, &cs);
          float o1 = (v[n] * cs - v[n + 2] * sn) * qs;
          float o2 = (v[n + 2] * cs + v[n] * sn) * qs;
          dst[base + d1]      = f2bf(o1);
          dst[base + d1 + 32] = f2bf(o2);
        }
      }
    }
  }
}

// ---------------- flash attention (byte-identical R6 structure) ----------------

template<bool MASKED>
__device__ __forceinline__ void attn_tile(int kv0, int qi, int half,
    const u16* __restrict__ Kh, const u16* __restrict__ Vh,
    short8 qf0, short8 qf1, short8 qf2, short8 qf3,
    f32x16& acc0, f32x16& acc1, float& m, float& l) {
  const u16* kp = Kh + (size_t)(kv0 + qi) * DH + half * 8;
  short8 k0 = *(const short8*)(kp);
  short8 k1 = *(const short8*)(kp + 16);
  short8 k2 = *(const short8*)(kp + 32);
  short8 k3 = *(const short8*)(kp + 48);
  __builtin_amdgcn_s_setprio(1);
  f32x16 sc = {0,0,0,0,0,0,0,0,0,0,0,0,0,0,0,0};
  sc = mfma32(k0, qf0, sc);
  sc = mfma32(k1, qf1, sc);
  sc = mfma32(k2, qf2, sc);
  sc = mfma32(k3, qf3, sc);
  __builtin_amdgcn_s_setprio(0);
  const u16* vp = Vh + (size_t)qi * S_LEN + kv0 + half * 8;
  short8 v00 = *(const short8*)(vp);
  short8 v01 = *(const short8*)(vp + 16);
  short8 v10 = *(const short8*)(vp + (size_t)32 * S_LEN);
  short8 v11 = *(const short8*)(vp + (size_t)32 * S_LEN + 16);
  if (MASKED) {
#pragma unroll
    for (int i = 0; i < 16; i++) {
      int kl = (i & 3) + 8 * (i >> 2) + 4 * half;
      if (kl > qi) sc[i] = -1e30f;
    }
  }
  float t0 = fmaxf(fmaxf(sc[0], sc[1]), fmaxf(sc[2], sc[3]));
  float t1 = fmaxf(fmaxf(sc[4], sc[5]), fmaxf(sc[6], sc[7]));
  float t2 = fmaxf(fmaxf(sc[8], sc[9]), fmaxf(sc[10], sc[11]));
  float t3 = fmaxf(fmaxf(sc[12], sc[13]), fmaxf(sc[14], sc[15]));
  float rmax = pr_max(fmaxf(fmaxf(t0, t1), fmaxf(t2, t3)));
  if (__any(rmax > m + 8.0f)) {
    float mn = fmaxf(m, rmax);
    float f = fexp2(m - mn);
    m = mn; l *= f;
#pragma unroll
    for (int i = 0; i < 16; i++) { acc0[i] *= f; acc1[i] *= f; }
  }
  f32x16 p;
#pragma unroll
  for (int i = 0; i < 16; i++) p[i] = fexp2(sc[i] - m);
  l += ((p[0] + p[1]) + (p[2] + p[3])) + ((p[4] + p[5]) + (p[6] + p[7]))
     + ((p[8] + p[9]) + (p[10] + p[11])) + ((p[12] + p[13]) + (p[14] + p[15]));
  bool hi = (half != 0);
  short8 pa0 = pack_frag(cvtpk(p[0], p[1]),   cvtpk(p[2], p[3]),
                         cvtpk(p[4], p[5]),   cvtpk(p[6], p[7]), hi);
  short8 pa1 = pack_frag(cvtpk(p[8], p[9]),   cvtpk(p[10], p[11]),
                         cvtpk(p[12], p[13]), cvtpk(p[14], p[15]), hi);
  __builtin_amdgcn_s_setprio(1);
  acc0 = mfma32(v00, pa0, acc0);
  acc0 = mfma32(v01, pa1, acc0);
  acc1 = mfma32(v10, pa0, acc1);
  acc1 = mfma32(v11, pa1, acc1);
  __builtin_amdgcn_s_setprio(0);
}

// two unmasked 32-KV tiles per call
__device__ __forceinline__ void attn_tile2(int kv0, int qi, int half,
    const u16* __restrict__ Kh, const u16* __restrict__ Vh,
    short8 qf0, short8 qf1, short8 qf2, short8 qf3,
    f32x16& acc0, f32x16& acc1, float& m, float& l) {
  const u16* kpa = Kh + (size_t)(kv0 + qi) * DH + half * 8;
  const u16* kpb = kpa + (size_t)32 * DH;
  short8 ka0 = *(const short8*)(kpa);
  short8 ka1 = *(const short8*)(kpa + 16);
  short8 ka2 = *(const short8*)(kpa + 32);
  short8 ka3 = *(const short8*)(kpa + 48);
  short8 kb0 = *(const short8*)(kpb);
  short8 kb1 = *(const short8*)(kpb + 16);
  short8 kb2 = *(const short8*)(kpb + 32);
  short8 kb3 = *(const short8*)(kpb + 48);
  __builtin_amdgcn_s_setprio(1);
  f32x16 sa = {0,0,0,0,0,0,0,0,0,0,0,0,0,0,0,0};
  f32x16 sb = {0,0,0,0,0,0,0,0,0,0,0,0,0,0,0,0};
  sa = mfma32(ka0, qf0, sa);
  sb = mfma32(kb0, qf0, sb);
  sa = mfma32(ka1, qf1, sa);
  sb = mfma32(kb1, qf1, sb);
  sa = mfma32(ka2, qf2, sa);
  sb = mfma32(kb2, qf2, sb);
  sa = mfma32(ka3, qf3, sa);
  sb = mfma32(kb3, qf3, sb);
  __builtin_amdgcn_s_setprio(0);
  const u16* vpa = Vh + (size_t)qi * S_LEN + kv0 + half * 8;
  const u16* vpb = vpa + 32;
  short8 va00 = *(const short8*)(vpa);
  short8 va01 = *(const short8*)(vpa + 16);
  short8 va10 = *(const short8*)(vpa + (size_t)32 * S_LEN);
  short8 va11 = *(const short8*)(vpa + (size_t)32 * S_LEN + 16);
  short8 vb00 = *(const short8*)(vpb);
  short8 vb01 = *(const short8*)(vpb + 16);
  short8 vb10 = *(const short8*)(vpb + (size_t)32 * S_LEN);
  short8 vb11 = *(const short8*)(vpb + (size_t)32 * S_LEN + 16);
  float t0 = fmaxf(fmaxf(sa[0], sa[1]), fmaxf(sa[2], sa[3]));
  float t1 = fmaxf(fmaxf(sa[4], sa[5]), fmaxf(sa[6], sa[7]));
  float t2 = fmaxf(fmaxf(sa[8], sa[9]), fmaxf(sa[10], sa[11]));
  float t3 = fmaxf(fmaxf(sa[12], sa[13]), fmaxf(sa[14], sa[15]));
  float u0 = fmaxf(fmaxf(sb[0], sb[1]), fmaxf(sb[2], sb[3]));
  float u1 = fmaxf(fmaxf(sb[4], sb[5]), fmaxf(sb[6], sb[7]));
  float u2 = fmaxf(fmaxf(sb[8], sb[9]), fmaxf(sb[10], sb[11]));
  float u3 = fmaxf(fmaxf(sb[12], sb[13]), fmaxf(sb[14], sb[15]));
  float rmax = pr_max(fmaxf(fmaxf(fmaxf(t0, t1), fmaxf(t2, t3)),
                            fmaxf(fmaxf(u0, u1), fmaxf(u2, u3))));
  if (__any(rmax > m + 8.0f)) {
    float mn = fmaxf(m, rmax);
    float f = fexp2(m - mn);
    m = mn; l *= f;
#pragma unroll
    for (int i = 0; i < 16; i++) { acc0[i] *= f; acc1[i] *= f; }
  }
  f32x16 pa, pb;
#pragma unroll
  for (int i = 0; i < 16; i++) pa[i] = fexp2(sa[i] - m);
#pragma unroll
  for (int i = 0; i < 16; i++) pb[i] = fexp2(sb[i] - m);
  float la = ((pa[0] + pa[1]) + (pa[2] + pa[3])) + ((pa[4] + pa[5]) + (pa[6] + pa[7]))
           + ((pa[8] + pa[9]) + (pa[10] + pa[11])) + ((pa[12] + pa[13]) + (pa[14] + pa[15]));
  float lb = ((pb[0] + pb[1]) + (pb[2] + pb[3])) + ((pb[4] + pb[5]) + (pb[6] + pb[7]))
           + ((pb[8] + pb[9]) + (pb[10] + pb[11])) + ((pb[12] + pb[13]) + (pb[14] + pb[15]));
  l += la + lb;
  bool hi = (half != 0);
  short8 fa0 = pack_frag(cvtpk(pa[0], pa[1]),   cvtpk(pa[2], pa[3]),
                         cvtpk(pa[4], pa[5]),   cvtpk(pa[6], pa[7]), hi);
  short8 fa1 = pack_frag(cvtpk(pa[8], pa[9]),   cvtpk(pa[10], pa[11]),
                         cvtpk(pa[12], pa[13]), cvtpk(pa[14], pa[15]), hi);
  short8 fb0 = pack_frag(cvtpk(pb[0], pb[1]),   cvtpk(pb[2], pb[3]),
                         cvtpk(pb[4], pb[5]),   cvtpk(pb[6], pb[7]), hi);
  short8 fb1 = pack_frag(cvtpk(pb[8], pb[9]),   cvtpk(pb[10], pb[11]),
                         cvtpk(pb[12], pb[13]), cvtpk(pb[14], pb[15]), hi);
  __builtin_amdgcn_s_setprio(1);
  acc0 = mfma32(va00, fa0, acc0);
  acc1 = mfma32(va10, fa0, acc1);
  acc0 = mfma32(va01, fa1, acc0);
  acc1 = mfma32(va11, fa1, acc1);
  acc0 = mfma32(vb00, fb0, acc0);
  acc1 = mfma32(vb10, fb0, acc1);
  acc0 = mfma32(vb01, fb1, acc0);
  acc1 = mfma32(vb11, fb1, acc1);
  __builtin_amdgcn_s_setprio(0);
}

__global__ __launch_bounds__(256, 3) void k_attn(const u16* __restrict__ Q,
                                                 const u16* __restrict__ K,
                                                 const u16* __restrict__ Vt,
                                                 u16* __restrict__ O) {
  __shared__ float Lacc[3][64][33];
  __shared__ float Lml[2][3][32];

  int t = threadIdx.x;
  int w = t >> 6, lane = t & 63;
  int qi = lane & 31, half = lane >> 5;
  int b = blockIdx.x;
  int h = b % NH;
  int qb = 127 - b / NH;              // longest blocks first

  const u16* Qh = Q  + (size_t)h * S_LEN * DH;
  const u16* Kh = K  + (size_t)h * S_LEN * DH;
  const u16* Vh = Vt + (size_t)h * DH * S_LEN;

  const u16* qp = Qh + (size_t)(qb * 32 + qi) * DH + half * 8;
  short8 qf0 = *(const short8*)(qp);
  short8 qf1 = *(const short8*)(qp + 16);
  short8 qf2 = *(const short8*)(qp + 32);
  short8 qf3 = *(const short8*)(qp + 48);

  f32x16 acc0 = {0,0,0,0,0,0,0,0,0,0,0,0,0,0,0,0};
  f32x16 acc1 = {0,0,0,0,0,0,0,0,0,0,0,0,0,0,0,0};
  float m = -1e30f, l = 0.f;

  int nt = qb + 1;                     // total KV tiles (last one masked)
  int ck = (nt + 3) >> 2;              // tiles per wave
  int start = w * ck;
  int end   = min(start + ck, nt);
  int endu  = min(end, nt - 1);        // unmasked range end
  int tt = start;
#pragma unroll 1
  for (; tt + 1 < endu; tt += 2)
    attn_tile2(tt * 32, qi, half, Kh, Vh, qf0, qf1, qf2, qf3, acc0, acc1, m, l);
  for (; tt < endu; tt++)
    attn_tile<false>(tt * 32, qi, half, Kh, Vh, qf0, qf1, qf2, qf3, acc0, acc1, m, l);
  if (start < nt && end == nt)
    attn_tile<true>((nt - 1) * 32, qi, half, Kh, Vh, qf0, qf1, qf2, qf3, acc0, acc1, m, l);

  // cross-wave merge
  float l2 = pr_add(l);
  if (w > 0) {
#pragma unroll
    for (int i = 0; i < 16; i++) {
      Lacc[w - 1][lane][i]      = acc0[i];
      Lacc[w - 1][lane][16 + i] = acc1[i];
    }
    if (half == 0) { Lml[0][w - 1][qi] = m; Lml[1][w - 1][qi] = l2; }
  }
  __syncthreads();
  if (w == 0) {
    float mw[3], lw[3];
    float M = m;
#pragma unroll
    for (int j = 0; j < 3; j++) { mw[j] = Lml[0][j][qi]; lw[j] = Lml[1][j][qi]; M = fmaxf(M, mw[j]); }
    float f0 = fexp2(m - M);
    float ltot = l2 * f0;
#pragma unroll
    for (int i = 0; i < 16; i++) { acc0[i] *= f0; acc1[i] *= f0; }
#pragma unroll
    for (int j = 0; j < 3; j++) {
      float fj = fexp2(mw[j] - M);
      ltot += lw[j] * fj;
#pragma unroll
      for (int i = 0; i < 16; i++) {
        acc0[i] += fj * Lacc[j][lane][i];
        acc1[i] += fj * Lacc[j][lane][16 + i];
      }
    }
    float rl = 1.0f / ltot;
    u16* orow = O + (size_t)(qb * 32 + qi) * EMB + h * DH;
#pragma unroll
    for (int i = 0; i < 16; i += 2) {
      int dl = (i & 3) + 8 * (i >> 2) + 4 * half;
      u32 wa = cvtpk(acc0[i] * rl, acc0[i + 1] * rl);
      u32 wb = cvtpk(acc1[i] * rl, acc1[i + 1] * rl);
      *(u32*)(orow + dl)      = wa;
      *(u32*)(orow + 32 + dl) = wb;
    }
  }
}

// ---------------- output projection (128x64 tiles, global_load_lds) ----------------
__global__ __launch_bounds__(256) void k_out(const u16* __restrict__ A,
                                             const u16* __restrict__ Bt,
                                             const float* __restrict__ bias,
                                             float* __restrict__ out) {
  __shared__ u16 AsL[128 * 32];
  __shared__ u16 BsL[64 * 32];
  int t = threadIdx.x;
  int w = t >> 6, lane = t & 63, g = lane >> 4, c = lane & 15;
  int bm = blockIdx.x * 128, bn = blockIdx.y * 64;

  f32x4 acc[2][4];
#pragma unroll
  for (int m = 0; m < 2; m++)
#pragma unroll
    for (int n = 0; n < 4; n++) acc[m][n] = (f32x4){0.f, 0.f, 0.f, 0.f};

  int r0 = t >> 2, cc0 = (t & 3) * 8;
  int r1 = (256 + t) >> 2;
  const u16* ga0 = A  + (size_t)(bm + r0) * EMB + cc0;
  const u16* ga1 = A  + (size_t)(bm + r1) * EMB + cc0;
  const u16* gb0 = Bt + (size_t)(bn + r0) * EMB + cc0;   // 64 rows x 4 chunks

  for (int bk = 0; bk < EMB; bk += 32) {
    __syncthreads();
    gld16(ga0 + bk, &AsL[(size_t)t * 8]);
    gld16(ga1 + bk, &AsL[(size_t)(256 + t) * 8]);
    gld16(gb0 + bk, &BsL[(size_t)t * 8]);
    __syncthreads();
    short8 af[2], bf[4];
#pragma unroll
    for (int m = 0; m < 2; m++) af[m] = *(const short8*)&AsL[(w * 32 + m * 16 + c) * 32 + g * 8];
#pragma unroll
    for (int n = 0; n < 4; n++) bf[n] = *(const short8*)&BsL[(n * 16 + c) * 32 + g * 8];
#pragma unroll
    for (int m = 0; m < 2; m++)
#pragma unroll
      for (int n = 0; n < 4; n++) acc[m][n] = mfma16(af[m], bf[n], acc[m][n]);
  }
#pragma unroll
  for (int m = 0; m < 2; m++) {
    int rowb = bm + w * 32 + m * 16 + 4 * g;
#pragma unroll
    for (int e = 0; e < 4; e++) {
      int srw = rowb + e;
#pragma unroll
      for (int n = 0; n < 4; n++) {
        int col = bn + n * 16 + c;
        out[(size_t)srw * EMB + col] = acc[m][n][e] + bias[col];
      }
    }
  }
}

// ---------------- launcher ----------------

extern "C" void kernel_launch(void* const* d_in, const int* in_sizes, int n_in,
                              void* d_out, int out_size, void* d_ws, size_t ws_size,
                              hipStream_t stream) {
  const float* x    = (const float*)d_in[0];
  const float* Wqkv = (const float*)d_in[2];
  const float* bqkv = (const float*)d_in[3];
  const float* Wout = (const float*)d_in[4];
  const float* bout = (const float*)d_in[5];
  float* out = (float*)d_out;

  char* ws = (char*)d_ws;
  u16* xb     = (u16*)(ws);
  u16* wqkvt  = (u16*)(ws + 6291456);
  u16* woutt  = (u16*)(ws + 9830400);
  u16* Qb     = (u16*)(ws + 11010048);
  u16* Kb     = (u16*)(ws + 17301504);
  u16* Vtb    = (u16*)(ws + 23592960);
  u16* Ob     = (u16*)(ws + 29884416);

  k_prep<<<3840, 256, 0, stream>>>(x, xb, Wqkv, wqkvt, Wout, woutt);
  k_qkv<<<dim3(32, 18), 256, 0, stream>>>(xb, wqkvt, bqkv, Qb, Kb, Vtb);
  k_attn<<<NH * 128, 256, 0, stream>>>(Qb, Kb, Vtb, Ob);
  k_out<<<dim3(32, 12), 256, 0, stream>>>(Ob, woutt, bout, out);
}